// Round 1
// baseline (2195.833 us; speedup 1.0000x reference)
//
#include <hip/hip_runtime.h>

#define NN 100000
#define NE 800000
#define DD 96

// workspace layout (floats)
#define OFF_DEG     0u
#define OFF_STATS   100000u          // 384 floats: sum1,sumsq1,sum2,sumsq2
#define OFF_PARAMS  100384u          // 384 floats: a1,b1,a2,b2
#define OFF_AGGSUM  101024u          // N*D, becomes o1
#define OFF_AGGMAX  (OFF_AGGSUM + 9600000u)  // N*D, becomes o2
#define OFF_HP      (OFF_AGGMAX + 9600000u)  // N*D

// ---------------- scatter add (mean aggregator numerator) + degree ----------------
__global__ void scatter_add_kernel(const float* __restrict__ x,
                                   const int* __restrict__ src,
                                   const int* __restrict__ dst,
                                   float* __restrict__ agg,
                                   float* __restrict__ deg) {
  int tid = blockIdx.x * blockDim.x + threadIdx.x;
  if (tid >= NE * 24) return;
  int e = tid / 24, c4 = tid % 24;
  int s = src[e], d = dst[e];
  float4 v = reinterpret_cast<const float4*>(x + (size_t)s * DD)[c4];
  float* a = agg + (size_t)d * DD + (size_t)c4 * 4;
  atomicAdd(a + 0, v.x);
  atomicAdd(a + 1, v.y);
  atomicAdd(a + 2, v.z);
  atomicAdd(a + 3, v.w);
  if (c4 == 0) atomicAdd(deg + d, 1.0f);
}

// ---------------- scatter max (pool aggregator). hp >= 0 so int-compare works ----------------
__global__ void scatter_max_kernel(const float* __restrict__ hp,
                                   const int* __restrict__ src,
                                   const int* __restrict__ dst,
                                   float* __restrict__ aggmax) {
  int tid = blockIdx.x * blockDim.x + threadIdx.x;
  if (tid >= NE * 24) return;
  int e = tid / 24, c4 = tid % 24;
  int s = src[e], d = dst[e];
  float4 v = reinterpret_cast<const float4*>(hp + (size_t)s * DD)[c4];
  int* a = reinterpret_cast<int*>(aggmax + (size_t)d * DD + (size_t)c4 * 4);
  atomicMax(a + 0, __float_as_int(v.x));
  atomicMax(a + 1, __float_as_int(v.y));
  atomicMax(a + 2, __float_as_int(v.z));
  atomicMax(a + 3, __float_as_int(v.w));
}

// ---------------- hp = relu(x @ W_pool + b_pool) ----------------
// block 256 = 32 rows x 8 col-groups (12 cols each); W in LDS
__global__ void hp_kernel(const float* __restrict__ x,
                          const float* __restrict__ Wp,
                          const float* __restrict__ bp,
                          float* __restrict__ hp) {
  __shared__ float Wl[96 * 96];
  __shared__ float xs[32][100];
  int t = threadIdx.x;
  for (int i = t; i < 96 * 96 / 4; i += 256)
    reinterpret_cast<float4*>(Wl)[i] = reinterpret_cast<const float4*>(Wp)[i];
  int row0 = blockIdx.x * 32;
  for (int i = t; i < 32 * 24; i += 256) {
    int r = i / 24, c4 = (i % 24) * 4;
    float4 v = reinterpret_cast<const float4*>(x + (size_t)(row0 + r) * DD)[c4 / 4];
    xs[r][c4 + 0] = v.x; xs[r][c4 + 1] = v.y; xs[r][c4 + 2] = v.z; xs[r][c4 + 3] = v.w;
  }
  __syncthreads();
  int row = t >> 3, c0 = (t & 7) * 12;
  float acc[12];
#pragma unroll
  for (int j = 0; j < 12; ++j) acc[j] = bp[c0 + j];
  for (int k = 0; k < 96; ++k) {
    float a = xs[row][k];
    const float* w = &Wl[k * 96 + c0];
#pragma unroll
    for (int j = 0; j < 12; ++j) acc[j] = fmaf(a, w[j], acc[j]);
  }
  float* o = hp + (size_t)(row0 + row) * DD + c0;
#pragma unroll
  for (int j = 0; j < 12; ++j) o[j] = fmaxf(acc[j], 0.0f);
}

// ---------------- o = x @ Wself + h @ Wneigh  (h optionally scaled by 1/max(deg,1)) ----------------
// writes o in place over hbuf (block-local rows only, after staging to LDS)
__global__ void gemm_o_kernel(const float* __restrict__ x,
                              float* __restrict__ hbuf,
                              const float* __restrict__ deg,
                              int use_deg,
                              const float* __restrict__ Wself,
                              const float* __restrict__ Wneigh) {
  __shared__ float Ws[96 * 96];
  __shared__ float Wn[96 * 96];
  __shared__ float xs[32][100];
  __shared__ float hs[32][100];
  int t = threadIdx.x;
  for (int i = t; i < 96 * 96 / 4; i += 256) {
    reinterpret_cast<float4*>(Ws)[i] = reinterpret_cast<const float4*>(Wself)[i];
    reinterpret_cast<float4*>(Wn)[i] = reinterpret_cast<const float4*>(Wneigh)[i];
  }
  int row0 = blockIdx.x * 32;
  for (int i = t; i < 32 * 24; i += 256) {
    int r = i / 24, c4 = (i % 24) * 4;
    size_t off = (size_t)(row0 + r) * DD + c4;
    float4 vx = *reinterpret_cast<const float4*>(x + off);
    float4 vh = *reinterpret_cast<const float4*>(hbuf + off);
    float sc = 1.0f;
    if (use_deg) sc = 1.0f / fmaxf(deg[row0 + r], 1.0f);
    xs[r][c4 + 0] = vx.x; xs[r][c4 + 1] = vx.y; xs[r][c4 + 2] = vx.z; xs[r][c4 + 3] = vx.w;
    hs[r][c4 + 0] = vh.x * sc; hs[r][c4 + 1] = vh.y * sc;
    hs[r][c4 + 2] = vh.z * sc; hs[r][c4 + 3] = vh.w * sc;
  }
  __syncthreads();
  int row = t >> 3, c0 = (t & 7) * 12;
  float acc[12];
#pragma unroll
  for (int j = 0; j < 12; ++j) acc[j] = 0.0f;
  for (int k = 0; k < 96; ++k) {
    float a = xs[row][k], b = hs[row][k];
    const float* ws = &Ws[k * 96 + c0];
    const float* wn = &Wn[k * 96 + c0];
#pragma unroll
    for (int j = 0; j < 12; ++j) acc[j] = fmaf(a, ws[j], fmaf(b, wn[j], acc[j]));
  }
  float* o = hbuf + (size_t)(row0 + row) * DD + c0;
#pragma unroll
  for (int j = 0; j < 12; ++j) o[j] = acc[j];
}

// ---------------- column sums / sumsq for both outputs ----------------
__global__ void stats_kernel(const float* __restrict__ o1,
                             const float* __restrict__ o2,
                             float* __restrict__ stats) {
  int t = threadIdx.x;
  int c = t & 127, half = t >> 7;
  bool active = c < 96;
  float s1 = 0, q1 = 0, s2 = 0, q2 = 0;
  if (active) {
    for (int r = blockIdx.x * 2 + half; r < NN; r += gridDim.x * 2) {
      float v = o1[(size_t)r * DD + c];
      float w = o2[(size_t)r * DD + c];
      s1 += v; q1 += v * v; s2 += w; q2 += w * w;
    }
  }
  __shared__ float sm[384];
  for (int i = t; i < 384; i += 256) sm[i] = 0.0f;
  __syncthreads();
  if (active) {
    atomicAdd(&sm[c], s1);
    atomicAdd(&sm[96 + c], q1);
    atomicAdd(&sm[192 + c], s2);
    atomicAdd(&sm[288 + c], q2);
  }
  __syncthreads();
  for (int i = t; i < 384; i += 256) atomicAdd(&stats[i], sm[i]);
}

// ---------------- fold BN into per-column affine ----------------
__global__ void finalize_kernel(const float* __restrict__ stats,
                                const float* __restrict__ g1, const float* __restrict__ beta1,
                                const float* __restrict__ g2, const float* __restrict__ beta2,
                                float* __restrict__ params) {
  int c = threadIdx.x;
  if (c >= 96) return;
  const float inv_n = 1.0f / NN;
  float mu1 = stats[c] * inv_n;
  float var1 = fmaxf(stats[96 + c] * inv_n - mu1 * mu1, 0.0f);
  float is1 = rsqrtf(var1 + 1e-5f);
  float a1 = g1[c] * is1;
  params[c] = a1;
  params[96 + c] = beta1[c] - a1 * mu1;
  float mu2 = stats[192 + c] * inv_n;
  float var2 = fmaxf(stats[288 + c] * inv_n - mu2 * mu2, 0.0f);
  float is2 = rsqrtf(var2 + 1e-5f);
  float a2 = g2[c] * is2;
  params[192 + c] = a2;
  params[288 + c] = beta2[c] - a2 * mu2;
}

// ---------------- out = leaky_relu(bn1(o1) + bn2(o2)) ----------------
__global__ void final_kernel(const float* __restrict__ o1,
                             const float* __restrict__ o2,
                             const float* __restrict__ params,
                             float* __restrict__ out) {
  int i = blockIdx.x * blockDim.x + threadIdx.x;
  if (i >= NN * 24) return;
  int c4 = i % 24;
  float4 v1 = reinterpret_cast<const float4*>(o1)[i];
  float4 v2 = reinterpret_cast<const float4*>(o2)[i];
  float4 A1 = reinterpret_cast<const float4*>(params)[c4];
  float4 B1 = reinterpret_cast<const float4*>(params + 96)[c4];
  float4 A2 = reinterpret_cast<const float4*>(params + 192)[c4];
  float4 B2 = reinterpret_cast<const float4*>(params + 288)[c4];
  float4 o;
  o.x = A1.x * v1.x + B1.x + A2.x * v2.x + B2.x;
  o.y = A1.y * v1.y + B1.y + A2.y * v2.y + B2.y;
  o.z = A1.z * v1.z + B1.z + A2.z * v2.z + B2.z;
  o.w = A1.w * v1.w + B1.w + A2.w * v2.w + B2.w;
  o.x = o.x > 0.0f ? o.x : 0.01f * o.x;
  o.y = o.y > 0.0f ? o.y : 0.01f * o.y;
  o.z = o.z > 0.0f ? o.z : 0.01f * o.z;
  o.w = o.w > 0.0f ? o.w : 0.01f * o.w;
  reinterpret_cast<float4*>(out)[i] = o;
}

extern "C" void kernel_launch(void* const* d_in, const int* in_sizes, int n_in,
                              void* d_out, int out_size, void* d_ws, size_t ws_size,
                              hipStream_t stream) {
  const float* x       = (const float*)d_in[0];
  const int*   ei      = (const int*)d_in[1];      // [2, E]: src then dst
  const float* W_self1 = (const float*)d_in[2];
  const float* W_neigh1= (const float*)d_in[3];
  const float* W_pool  = (const float*)d_in[4];
  const float* b_pool  = (const float*)d_in[5];
  const float* W_self2 = (const float*)d_in[6];
  const float* W_neigh2= (const float*)d_in[7];
  const float* g1      = (const float*)d_in[8];
  const float* beta1   = (const float*)d_in[9];
  const float* g2      = (const float*)d_in[10];
  const float* beta2   = (const float*)d_in[11];
  float* out = (float*)d_out;

  float* ws = (float*)d_ws;
  float* deg    = ws + OFF_DEG;
  float* stats  = ws + OFF_STATS;
  float* params = ws + OFF_PARAMS;
  float* aggsum = ws + OFF_AGGSUM;   // becomes o1
  float* aggmax = ws + OFF_AGGMAX;   // becomes o2
  float* hp     = ws + OFF_HP;

  const int* src = ei;
  const int* dst = ei + NE;

  // zero: deg+stats, aggsum+aggmax (contiguous)
  hipMemsetAsync(ws, 0, (100000u + 384u) * sizeof(float), stream);
  hipMemsetAsync(aggsum, 0, (size_t)2 * NN * DD * sizeof(float), stream);

  // scatter-add + degree
  scatter_add_kernel<<<(NE * 24 + 255) / 256, 256, 0, stream>>>(x, src, dst, aggsum, deg);

  // hp = relu(x @ W_pool + b)
  hp_kernel<<<NN / 32, 256, 0, stream>>>(x, W_pool, b_pool, hp);

  // scatter-max
  scatter_max_kernel<<<(NE * 24 + 255) / 256, 256, 0, stream>>>(hp, src, dst, aggmax);

  // o1 = x@W_self1 + (aggsum/deg)@W_neigh1   (in place over aggsum)
  gemm_o_kernel<<<NN / 32, 256, 0, stream>>>(x, aggsum, deg, 1, W_self1, W_neigh1);
  // o2 = x@W_self2 + aggmax@W_neigh2         (in place over aggmax)
  gemm_o_kernel<<<NN / 32, 256, 0, stream>>>(x, aggmax, deg, 0, W_self2, W_neigh2);

  // BN stats, fold, final combine
  stats_kernel<<<512, 256, 0, stream>>>(aggsum, aggmax, stats);
  finalize_kernel<<<1, 128, 0, stream>>>(stats, g1, beta1, g2, beta2, params);
  final_kernel<<<(NN * 24 + 255) / 256, 256, 0, stream>>>(aggsum, aggmax, params, out);
}

// Round 2
// 800.215 us; speedup vs baseline: 2.7441x; 2.7441x over previous
//
#include <hip/hip_runtime.h>

#define NN 100000
#define NE 800000
#define DD 96

// workspace layout (4-byte element offsets)
#define OFF_DEG      0u                         // NN ints
#define OFF_ROWSTART 100000u                    // NN+1 ints
#define OFF_CURSOR   200004u                    // NN ints
#define OFF_STATS    300004u                    // 384 floats
#define OFF_PARAMS   300388u                    // 384 floats
#define OFF_CSR      300772u                    // NE ints
#define OFF_AGGMEAN  1100772u                   // N*D floats, becomes o1
#define OFF_AGGMAX   (OFF_AGGMEAN + 9600000u)   // N*D floats, becomes o2
#define OFF_HP       (OFF_AGGMAX + 9600000u)    // N*D floats

// ---------------- degree histogram ----------------
__global__ void deg_kernel(const int* __restrict__ dst, int* __restrict__ deg) {
  int e = blockIdx.x * blockDim.x + threadIdx.x;
  if (e >= NE) return;
  atomicAdd(&deg[dst[e]], 1);
}

// ---------------- exclusive scan of deg -> row_start (and cursor copy) ----------------
__global__ void scan_kernel(const int* __restrict__ deg,
                            int* __restrict__ row_start,
                            int* __restrict__ cursor) {
  __shared__ int partial[1024];
  int t = threadIdx.x;
  const int CHUNK = (NN + 1023) / 1024;  // 98
  int base = t * CHUNK;
  int sum = 0;
  for (int i = 0; i < CHUNK; ++i) {
    int idx = base + i;
    if (idx < NN) sum += deg[idx];
  }
  partial[t] = sum;
  __syncthreads();
  for (int off = 1; off < 1024; off <<= 1) {
    int v = 0;
    if (t >= off) v = partial[t - off];
    __syncthreads();
    if (t >= off) partial[t] += v;
    __syncthreads();
  }
  int run = (t == 0) ? 0 : partial[t - 1];
  for (int i = 0; i < CHUNK; ++i) {
    int idx = base + i;
    if (idx < NN) {
      row_start[idx] = run;
      cursor[idx] = run;
      run += deg[idx];
    }
  }
  if (t == 1023) row_start[NN] = partial[1023];
}

// ---------------- fill CSR: csr[pos] = src for each (src,dst) ----------------
__global__ void fill_csr_kernel(const int* __restrict__ src,
                                const int* __restrict__ dst,
                                int* __restrict__ cursor,
                                int* __restrict__ csr) {
  int e = blockIdx.x * blockDim.x + threadIdx.x;
  if (e >= NE) return;
  int pos = atomicAdd(&cursor[dst[e]], 1);
  csr[pos] = src[e];
}

// ---------------- hp = relu(x @ W_pool + b_pool) ----------------
__global__ void hp_kernel(const float* __restrict__ x,
                          const float* __restrict__ Wp,
                          const float* __restrict__ bp,
                          float* __restrict__ hp) {
  __shared__ float Wl[96 * 96];
  __shared__ float xs[32][100];
  int t = threadIdx.x;
  for (int i = t; i < 96 * 96 / 4; i += 256)
    reinterpret_cast<float4*>(Wl)[i] = reinterpret_cast<const float4*>(Wp)[i];
  int row0 = blockIdx.x * 32;
  for (int i = t; i < 32 * 24; i += 256) {
    int r = i / 24, c4 = (i % 24) * 4;
    float4 v = reinterpret_cast<const float4*>(x + (size_t)(row0 + r) * DD)[c4 / 4];
    xs[r][c4 + 0] = v.x; xs[r][c4 + 1] = v.y; xs[r][c4 + 2] = v.z; xs[r][c4 + 3] = v.w;
  }
  __syncthreads();
  int row = t >> 3, c0 = (t & 7) * 12;
  float acc[12];
#pragma unroll
  for (int j = 0; j < 12; ++j) acc[j] = bp[c0 + j];
  for (int k = 0; k < 96; ++k) {
    float a = xs[row][k];
    const float* w = &Wl[k * 96 + c0];
#pragma unroll
    for (int j = 0; j < 12; ++j) acc[j] = fmaf(a, w[j], acc[j]);
  }
  float* o = hp + (size_t)(row0 + row) * DD + c0;
#pragma unroll
  for (int j = 0; j < 12; ++j) o[j] = fmaxf(acc[j], 0.0f);
}

// ---------------- fused gather: aggmean = mean x[nbr], aggmax = max hp[nbr] ----------------
// 8 threads per node, 32 nodes per 256-block
__global__ void gather_kernel(const float* __restrict__ x,
                              const float* __restrict__ hp,
                              const int* __restrict__ row_start,
                              const int* __restrict__ csr,
                              float* __restrict__ aggmean,
                              float* __restrict__ aggmax) {
  int t = threadIdx.x;
  int node = blockIdx.x * 32 + (t >> 3);
  int lane = t & 7;
  int beg = row_start[node], end = row_start[node + 1];
  float4 s0 = {0, 0, 0, 0}, s1 = s0, s2 = s0;
  float4 m0 = s0, m1 = s0, m2 = s0;
  for (int i = beg; i < end; ++i) {
    int srow = csr[i];
    const float4* xr = reinterpret_cast<const float4*>(x + (size_t)srow * DD);
    const float4* hr = reinterpret_cast<const float4*>(hp + (size_t)srow * DD);
    float4 a = xr[lane], b = xr[lane + 8], c = xr[lane + 16];
    float4 ha = hr[lane], hb = hr[lane + 8], hc = hr[lane + 16];
    s0.x += a.x; s0.y += a.y; s0.z += a.z; s0.w += a.w;
    s1.x += b.x; s1.y += b.y; s1.z += b.z; s1.w += b.w;
    s2.x += c.x; s2.y += c.y; s2.z += c.z; s2.w += c.w;
    m0.x = fmaxf(m0.x, ha.x); m0.y = fmaxf(m0.y, ha.y);
    m0.z = fmaxf(m0.z, ha.z); m0.w = fmaxf(m0.w, ha.w);
    m1.x = fmaxf(m1.x, hb.x); m1.y = fmaxf(m1.y, hb.y);
    m1.z = fmaxf(m1.z, hb.z); m1.w = fmaxf(m1.w, hb.w);
    m2.x = fmaxf(m2.x, hc.x); m2.y = fmaxf(m2.y, hc.y);
    m2.z = fmaxf(m2.z, hc.z); m2.w = fmaxf(m2.w, hc.w);
  }
  float inv = (end > beg) ? 1.0f / (float)(end - beg) : 0.0f;
  s0.x *= inv; s0.y *= inv; s0.z *= inv; s0.w *= inv;
  s1.x *= inv; s1.y *= inv; s1.z *= inv; s1.w *= inv;
  s2.x *= inv; s2.y *= inv; s2.z *= inv; s2.w *= inv;
  float4* om = reinterpret_cast<float4*>(aggmean + (size_t)node * DD);
  float4* ox = reinterpret_cast<float4*>(aggmax + (size_t)node * DD);
  om[lane] = s0; om[lane + 8] = s1; om[lane + 16] = s2;
  ox[lane] = m0; ox[lane + 8] = m1; ox[lane + 16] = m2;
}

// ---------------- o = x @ Wself + h @ Wneigh (in place over hbuf) ----------------
__global__ void gemm_o_kernel(const float* __restrict__ x,
                              float* __restrict__ hbuf,
                              const float* __restrict__ Wself,
                              const float* __restrict__ Wneigh) {
  __shared__ float Ws[96 * 96];
  __shared__ float Wn[96 * 96];
  __shared__ float xs[32][100];
  __shared__ float hs[32][100];
  int t = threadIdx.x;
  for (int i = t; i < 96 * 96 / 4; i += 256) {
    reinterpret_cast<float4*>(Ws)[i] = reinterpret_cast<const float4*>(Wself)[i];
    reinterpret_cast<float4*>(Wn)[i] = reinterpret_cast<const float4*>(Wneigh)[i];
  }
  int row0 = blockIdx.x * 32;
  for (int i = t; i < 32 * 24; i += 256) {
    int r = i / 24, c4 = (i % 24) * 4;
    size_t off = (size_t)(row0 + r) * DD + c4;
    float4 vx = *reinterpret_cast<const float4*>(x + off);
    float4 vh = *reinterpret_cast<const float4*>(hbuf + off);
    xs[r][c4 + 0] = vx.x; xs[r][c4 + 1] = vx.y; xs[r][c4 + 2] = vx.z; xs[r][c4 + 3] = vx.w;
    hs[r][c4 + 0] = vh.x; hs[r][c4 + 1] = vh.y; hs[r][c4 + 2] = vh.z; hs[r][c4 + 3] = vh.w;
  }
  __syncthreads();
  int row = t >> 3, c0 = (t & 7) * 12;
  float acc[12];
#pragma unroll
  for (int j = 0; j < 12; ++j) acc[j] = 0.0f;
  for (int k = 0; k < 96; ++k) {
    float a = xs[row][k], b = hs[row][k];
    const float* ws = &Ws[k * 96 + c0];
    const float* wn = &Wn[k * 96 + c0];
#pragma unroll
    for (int j = 0; j < 12; ++j) acc[j] = fmaf(a, ws[j], fmaf(b, wn[j], acc[j]));
  }
  float* o = hbuf + (size_t)(row0 + row) * DD + c0;
#pragma unroll
  for (int j = 0; j < 12; ++j) o[j] = acc[j];
}

// ---------------- column sums / sumsq for both outputs ----------------
__global__ void stats_kernel(const float* __restrict__ o1,
                             const float* __restrict__ o2,
                             float* __restrict__ stats) {
  int t = threadIdx.x;
  int c = t & 127, half = t >> 7;
  bool active = c < 96;
  float s1 = 0, q1 = 0, s2 = 0, q2 = 0;
  if (active) {
    for (int r = blockIdx.x * 2 + half; r < NN; r += gridDim.x * 2) {
      float v = o1[(size_t)r * DD + c];
      float w = o2[(size_t)r * DD + c];
      s1 += v; q1 += v * v; s2 += w; q2 += w * w;
    }
  }
  __shared__ float sm[384];
  for (int i = t; i < 384; i += 256) sm[i] = 0.0f;
  __syncthreads();
  if (active) {
    atomicAdd(&sm[c], s1);
    atomicAdd(&sm[96 + c], q1);
    atomicAdd(&sm[192 + c], s2);
    atomicAdd(&sm[288 + c], q2);
  }
  __syncthreads();
  for (int i = t; i < 384; i += 256) atomicAdd(&stats[i], sm[i]);
}

// ---------------- fold BN into per-column affine ----------------
__global__ void finalize_kernel(const float* __restrict__ stats,
                                const float* __restrict__ g1, const float* __restrict__ beta1,
                                const float* __restrict__ g2, const float* __restrict__ beta2,
                                float* __restrict__ params) {
  int c = threadIdx.x;
  if (c >= 96) return;
  const float inv_n = 1.0f / NN;
  float mu1 = stats[c] * inv_n;
  float var1 = fmaxf(stats[96 + c] * inv_n - mu1 * mu1, 0.0f);
  float is1 = rsqrtf(var1 + 1e-5f);
  float a1 = g1[c] * is1;
  params[c] = a1;
  params[96 + c] = beta1[c] - a1 * mu1;
  float mu2 = stats[192 + c] * inv_n;
  float var2 = fmaxf(stats[288 + c] * inv_n - mu2 * mu2, 0.0f);
  float is2 = rsqrtf(var2 + 1e-5f);
  float a2 = g2[c] * is2;
  params[192 + c] = a2;
  params[288 + c] = beta2[c] - a2 * mu2;
}

// ---------------- out = leaky_relu(bn1(o1) + bn2(o2)) ----------------
__global__ void final_kernel(const float* __restrict__ o1,
                             const float* __restrict__ o2,
                             const float* __restrict__ params,
                             float* __restrict__ out) {
  int i = blockIdx.x * blockDim.x + threadIdx.x;
  if (i >= NN * 24) return;
  int c4 = i % 24;
  float4 v1 = reinterpret_cast<const float4*>(o1)[i];
  float4 v2 = reinterpret_cast<const float4*>(o2)[i];
  float4 A1 = reinterpret_cast<const float4*>(params)[c4];
  float4 B1 = reinterpret_cast<const float4*>(params + 96)[c4];
  float4 A2 = reinterpret_cast<const float4*>(params + 192)[c4];
  float4 B2 = reinterpret_cast<const float4*>(params + 288)[c4];
  float4 o;
  o.x = A1.x * v1.x + B1.x + A2.x * v2.x + B2.x;
  o.y = A1.y * v1.y + B1.y + A2.y * v2.y + B2.y;
  o.z = A1.z * v1.z + B1.z + A2.z * v2.z + B2.z;
  o.w = A1.w * v1.w + B1.w + A2.w * v2.w + B2.w;
  o.x = o.x > 0.0f ? o.x : 0.01f * o.x;
  o.y = o.y > 0.0f ? o.y : 0.01f * o.y;
  o.z = o.z > 0.0f ? o.z : 0.01f * o.z;
  o.w = o.w > 0.0f ? o.w : 0.01f * o.w;
  reinterpret_cast<float4*>(out)[i] = o;
}

extern "C" void kernel_launch(void* const* d_in, const int* in_sizes, int n_in,
                              void* d_out, int out_size, void* d_ws, size_t ws_size,
                              hipStream_t stream) {
  const float* x       = (const float*)d_in[0];
  const int*   ei      = (const int*)d_in[1];      // [2, E]: src then dst
  const float* W_self1 = (const float*)d_in[2];
  const float* W_neigh1= (const float*)d_in[3];
  const float* W_pool  = (const float*)d_in[4];
  const float* b_pool  = (const float*)d_in[5];
  const float* W_self2 = (const float*)d_in[6];
  const float* W_neigh2= (const float*)d_in[7];
  const float* g1      = (const float*)d_in[8];
  const float* beta1   = (const float*)d_in[9];
  const float* g2      = (const float*)d_in[10];
  const float* beta2   = (const float*)d_in[11];
  float* out = (float*)d_out;

  float* ws = (float*)d_ws;
  int*   deg       = (int*)(ws + OFF_DEG);
  int*   row_start = (int*)(ws + OFF_ROWSTART);
  int*   cursor    = (int*)(ws + OFF_CURSOR);
  float* stats     = ws + OFF_STATS;
  float* params    = ws + OFF_PARAMS;
  int*   csr       = (int*)(ws + OFF_CSR);
  float* aggmean   = ws + OFF_AGGMEAN;   // becomes o1
  float* aggmax    = ws + OFF_AGGMAX;    // becomes o2
  float* hp        = ws + OFF_HP;

  const int* src = ei;
  const int* dst = ei + NE;

  // zero deg + stats region (deg at 0..NN, stats small block)
  hipMemsetAsync(deg, 0, NN * sizeof(int), stream);
  hipMemsetAsync(stats, 0, 384 * sizeof(float), stream);

  // CSR build
  deg_kernel<<<(NE + 255) / 256, 256, 0, stream>>>(dst, deg);
  scan_kernel<<<1, 1024, 0, stream>>>(deg, row_start, cursor);
  fill_csr_kernel<<<(NE + 255) / 256, 256, 0, stream>>>(src, dst, cursor, csr);

  // hp = relu(x @ W_pool + b)
  hp_kernel<<<NN / 32, 256, 0, stream>>>(x, W_pool, b_pool, hp);

  // fused gather (mean of x, max of hp)
  gather_kernel<<<NN / 32, 256, 0, stream>>>(x, hp, row_start, csr, aggmean, aggmax);

  // o1 = x@W_self1 + aggmean@W_neigh1   (in place over aggmean)
  gemm_o_kernel<<<NN / 32, 256, 0, stream>>>(x, aggmean, W_self1, W_neigh1);
  // o2 = x@W_self2 + aggmax@W_neigh2    (in place over aggmax)
  gemm_o_kernel<<<NN / 32, 256, 0, stream>>>(x, aggmax, W_self2, W_neigh2);

  // BN stats, fold, final combine
  stats_kernel<<<512, 256, 0, stream>>>(aggmean, aggmax, stats);
  finalize_kernel<<<1, 128, 0, stream>>>(stats, g1, beta1, g2, beta2, params);
  final_kernel<<<(NN * 24 + 255) / 256, 256, 0, stream>>>(aggmean, aggmax, params, out);
}

// Round 3
// 551.711 us; speedup vs baseline: 3.9800x; 1.4504x over previous
//
#include <hip/hip_runtime.h>

#define NN 100000
#define NE 800000
#define DD 96
#define SCAN_BLOCKS 100
#define SCAN_CHUNK 1000   // SCAN_BLOCKS * SCAN_CHUNK == NN

// workspace layout (4-byte element offsets)
#define OFF_DEG      0u                         // NN ints
#define OFF_ROWSTART 100000u                    // NN+1 ints
#define OFF_CURSOR   200004u                    // NN ints
#define OFF_BSUM     300004u                    // 128 ints (block sums)
#define OFF_STATS    300132u                    // 384 floats
#define OFF_PARAMS   300516u                    // 384 floats
#define OFF_CSR      300900u                    // NE ints
#define OFF_AGGMEAN  1100900u                   // N*D floats, becomes o1
#define OFF_AGGMAX   (OFF_AGGMEAN + 9600000u)   // N*D floats, becomes o2
#define OFF_HP       (OFF_AGGMAX + 9600000u)    // N*D floats

// ---------------- degree histogram ----------------
__global__ void deg_kernel(const int* __restrict__ dst, int* __restrict__ deg) {
  int e = blockIdx.x * blockDim.x + threadIdx.x;
  if (e >= NE) return;
  atomicAdd(&deg[dst[e]], 1);
}

// ---------------- scan phase 1: per-block sums (1000 elems/block) ----------------
__global__ void scan_sum_kernel(const int* __restrict__ deg, int* __restrict__ bsum) {
  __shared__ int red[256];
  int t = threadIdx.x;
  int base = blockIdx.x * SCAN_CHUNK;
  int s = 0;
  for (int i = t; i < SCAN_CHUNK; i += 256) s += deg[base + i];
  red[t] = s;
  __syncthreads();
  for (int off = 128; off > 0; off >>= 1) {
    if (t < off) red[t] += red[t + off];
    __syncthreads();
  }
  if (t == 0) bsum[blockIdx.x] = red[0];
}

// ---------------- scan phase 2: exclusive scan of 100 block sums ----------------
__global__ void scan_bsum_kernel(int* __restrict__ bsum, int* __restrict__ row_start) {
  __shared__ int sm[128];
  int t = threadIdx.x;
  int v = (t < SCAN_BLOCKS) ? bsum[t] : 0;
  sm[t] = v;
  __syncthreads();
  for (int off = 1; off < 128; off <<= 1) {
    int u = 0;
    if (t >= off) u = sm[t - off];
    __syncthreads();
    if (t >= off) sm[t] += u;
    __syncthreads();
  }
  // convert to exclusive
  if (t < SCAN_BLOCKS) bsum[t] = sm[t] - v;
  if (t == SCAN_BLOCKS - 1) row_start[NN] = sm[t];
}

// ---------------- scan phase 3: local exclusive scan + block offset ----------------
// 250 active threads x 4 contiguous elems each = 1000 per block
__global__ void scan_final_kernel(const int* __restrict__ deg,
                                  const int* __restrict__ bsum,
                                  int* __restrict__ row_start,
                                  int* __restrict__ cursor) {
  __shared__ int sm[256];
  int t = threadIdx.x;
  int base = blockIdx.x * SCAN_CHUNK + t * 4;
  int4 d = {0, 0, 0, 0};
  if (t < 250) d = *reinterpret_cast<const int4*>(deg + base);
  int tot = d.x + d.y + d.z + d.w;
  sm[t] = tot;
  __syncthreads();
  for (int off = 1; off < 256; off <<= 1) {
    int u = 0;
    if (t >= off) u = sm[t - off];
    __syncthreads();
    if (t >= off) sm[t] += u;
    __syncthreads();
  }
  if (t < 250) {
    int run = bsum[blockIdx.x] + sm[t] - tot;  // exclusive prefix
    int4 rs;
    rs.x = run;
    rs.y = run + d.x;
    rs.z = run + d.x + d.y;
    rs.w = run + d.x + d.y + d.z;
    *reinterpret_cast<int4*>(row_start + base) = rs;
    *reinterpret_cast<int4*>(cursor + base) = rs;
  }
}

// ---------------- fill CSR: csr[pos] = src for each (src,dst) ----------------
__global__ void fill_csr_kernel(const int* __restrict__ src,
                                const int* __restrict__ dst,
                                int* __restrict__ cursor,
                                int* __restrict__ csr) {
  int e = blockIdx.x * blockDim.x + threadIdx.x;
  if (e >= NE) return;
  int pos = atomicAdd(&cursor[dst[e]], 1);
  csr[pos] = src[e];
}

// ---------------- hp = relu(x @ W_pool + b_pool) ----------------
__global__ void hp_kernel(const float* __restrict__ x,
                          const float* __restrict__ Wp,
                          const float* __restrict__ bp,
                          float* __restrict__ hp) {
  __shared__ float Wl[96 * 96];
  __shared__ float xs[32][100];
  int t = threadIdx.x;
  for (int i = t; i < 96 * 96 / 4; i += 256)
    reinterpret_cast<float4*>(Wl)[i] = reinterpret_cast<const float4*>(Wp)[i];
  int row0 = blockIdx.x * 32;
  for (int i = t; i < 32 * 24; i += 256) {
    int r = i / 24, c4 = (i % 24) * 4;
    float4 v = reinterpret_cast<const float4*>(x + (size_t)(row0 + r) * DD)[c4 / 4];
    xs[r][c4 + 0] = v.x; xs[r][c4 + 1] = v.y; xs[r][c4 + 2] = v.z; xs[r][c4 + 3] = v.w;
  }
  __syncthreads();
  int row = t >> 3, c0 = (t & 7) * 12;
  float acc[12];
#pragma unroll
  for (int j = 0; j < 12; ++j) acc[j] = bp[c0 + j];
  for (int k = 0; k < 96; ++k) {
    float a = xs[row][k];
    const float* w = &Wl[k * 96 + c0];
#pragma unroll
    for (int j = 0; j < 12; ++j) acc[j] = fmaf(a, w[j], acc[j]);
  }
  float* o = hp + (size_t)(row0 + row) * DD + c0;
#pragma unroll
  for (int j = 0; j < 12; ++j) o[j] = fmaxf(acc[j], 0.0f);
}

// ---------------- fused gather: aggmean = mean x[nbr], aggmax = max hp[nbr] ----------------
__global__ void gather_kernel(const float* __restrict__ x,
                              const float* __restrict__ hp,
                              const int* __restrict__ row_start,
                              const int* __restrict__ csr,
                              float* __restrict__ aggmean,
                              float* __restrict__ aggmax) {
  int t = threadIdx.x;
  int node = blockIdx.x * 32 + (t >> 3);
  int lane = t & 7;
  int beg = row_start[node], end = row_start[node + 1];
  float4 s0 = {0, 0, 0, 0}, s1 = s0, s2 = s0;
  float4 m0 = s0, m1 = s0, m2 = s0;
  for (int i = beg; i < end; ++i) {
    int srow = csr[i];
    const float4* xr = reinterpret_cast<const float4*>(x + (size_t)srow * DD);
    const float4* hr = reinterpret_cast<const float4*>(hp + (size_t)srow * DD);
    float4 a = xr[lane], b = xr[lane + 8], c = xr[lane + 16];
    float4 ha = hr[lane], hb = hr[lane + 8], hc = hr[lane + 16];
    s0.x += a.x; s0.y += a.y; s0.z += a.z; s0.w += a.w;
    s1.x += b.x; s1.y += b.y; s1.z += b.z; s1.w += b.w;
    s2.x += c.x; s2.y += c.y; s2.z += c.z; s2.w += c.w;
    m0.x = fmaxf(m0.x, ha.x); m0.y = fmaxf(m0.y, ha.y);
    m0.z = fmaxf(m0.z, ha.z); m0.w = fmaxf(m0.w, ha.w);
    m1.x = fmaxf(m1.x, hb.x); m1.y = fmaxf(m1.y, hb.y);
    m1.z = fmaxf(m1.z, hb.z); m1.w = fmaxf(m1.w, hb.w);
    m2.x = fmaxf(m2.x, hc.x); m2.y = fmaxf(m2.y, hc.y);
    m2.z = fmaxf(m2.z, hc.z); m2.w = fmaxf(m2.w, hc.w);
  }
  float inv = (end > beg) ? 1.0f / (float)(end - beg) : 0.0f;
  s0.x *= inv; s0.y *= inv; s0.z *= inv; s0.w *= inv;
  s1.x *= inv; s1.y *= inv; s1.z *= inv; s1.w *= inv;
  s2.x *= inv; s2.y *= inv; s2.z *= inv; s2.w *= inv;
  float4* om = reinterpret_cast<float4*>(aggmean + (size_t)node * DD);
  float4* ox = reinterpret_cast<float4*>(aggmax + (size_t)node * DD);
  om[lane] = s0; om[lane + 8] = s1; om[lane + 16] = s2;
  ox[lane] = m0; ox[lane + 8] = m1; ox[lane + 16] = m2;
}

// ---------------- o = x @ Wself + h @ Wneigh (in place over hbuf) ----------------
__global__ void gemm_o_kernel(const float* __restrict__ x,
                              float* __restrict__ hbuf,
                              const float* __restrict__ Wself,
                              const float* __restrict__ Wneigh) {
  __shared__ float Ws[96 * 96];
  __shared__ float Wn[96 * 96];
  __shared__ float xs[32][100];
  __shared__ float hs[32][100];
  int t = threadIdx.x;
  for (int i = t; i < 96 * 96 / 4; i += 256) {
    reinterpret_cast<float4*>(Ws)[i] = reinterpret_cast<const float4*>(Wself)[i];
    reinterpret_cast<float4*>(Wn)[i] = reinterpret_cast<const float4*>(Wneigh)[i];
  }
  int row0 = blockIdx.x * 32;
  for (int i = t; i < 32 * 24; i += 256) {
    int r = i / 24, c4 = (i % 24) * 4;
    size_t off = (size_t)(row0 + r) * DD + c4;
    float4 vx = *reinterpret_cast<const float4*>(x + off);
    float4 vh = *reinterpret_cast<const float4*>(hbuf + off);
    xs[r][c4 + 0] = vx.x; xs[r][c4 + 1] = vx.y; xs[r][c4 + 2] = vx.z; xs[r][c4 + 3] = vx.w;
    hs[r][c4 + 0] = vh.x; hs[r][c4 + 1] = vh.y; hs[r][c4 + 2] = vh.z; hs[r][c4 + 3] = vh.w;
  }
  __syncthreads();
  int row = t >> 3, c0 = (t & 7) * 12;
  float acc[12];
#pragma unroll
  for (int j = 0; j < 12; ++j) acc[j] = 0.0f;
  for (int k = 0; k < 96; ++k) {
    float a = xs[row][k], b = hs[row][k];
    const float* ws = &Ws[k * 96 + c0];
    const float* wn = &Wn[k * 96 + c0];
#pragma unroll
    for (int j = 0; j < 12; ++j) acc[j] = fmaf(a, ws[j], fmaf(b, wn[j], acc[j]));
  }
  float* o = hbuf + (size_t)(row0 + row) * DD + c0;
#pragma unroll
  for (int j = 0; j < 12; ++j) o[j] = acc[j];
}

// ---------------- column sums / sumsq for both outputs ----------------
__global__ void stats_kernel(const float* __restrict__ o1,
                             const float* __restrict__ o2,
                             float* __restrict__ stats) {
  int t = threadIdx.x;
  int c = t & 127, half = t >> 7;
  bool active = c < 96;
  float s1 = 0, q1 = 0, s2 = 0, q2 = 0;
  if (active) {
    for (int r = blockIdx.x * 2 + half; r < NN; r += gridDim.x * 2) {
      float v = o1[(size_t)r * DD + c];
      float w = o2[(size_t)r * DD + c];
      s1 += v; q1 += v * v; s2 += w; q2 += w * w;
    }
  }
  __shared__ float sm[384];
  for (int i = t; i < 384; i += 256) sm[i] = 0.0f;
  __syncthreads();
  if (active) {
    atomicAdd(&sm[c], s1);
    atomicAdd(&sm[96 + c], q1);
    atomicAdd(&sm[192 + c], s2);
    atomicAdd(&sm[288 + c], q2);
  }
  __syncthreads();
  for (int i = t; i < 384; i += 256) atomicAdd(&stats[i], sm[i]);
}

// ---------------- fold BN into per-column affine ----------------
__global__ void finalize_kernel(const float* __restrict__ stats,
                                const float* __restrict__ g1, const float* __restrict__ beta1,
                                const float* __restrict__ g2, const float* __restrict__ beta2,
                                float* __restrict__ params) {
  int c = threadIdx.x;
  if (c >= 96) return;
  const float inv_n = 1.0f / NN;
  float mu1 = stats[c] * inv_n;
  float var1 = fmaxf(stats[96 + c] * inv_n - mu1 * mu1, 0.0f);
  float is1 = rsqrtf(var1 + 1e-5f);
  float a1 = g1[c] * is1;
  params[c] = a1;
  params[96 + c] = beta1[c] - a1 * mu1;
  float mu2 = stats[192 + c] * inv_n;
  float var2 = fmaxf(stats[288 + c] * inv_n - mu2 * mu2, 0.0f);
  float is2 = rsqrtf(var2 + 1e-5f);
  float a2 = g2[c] * is2;
  params[192 + c] = a2;
  params[288 + c] = beta2[c] - a2 * mu2;
}

// ---------------- out = leaky_relu(bn1(o1) + bn2(o2)) ----------------
__global__ void final_kernel(const float* __restrict__ o1,
                             const float* __restrict__ o2,
                             const float* __restrict__ params,
                             float* __restrict__ out) {
  int i = blockIdx.x * blockDim.x + threadIdx.x;
  if (i >= NN * 24) return;
  int c4 = i % 24;
  float4 v1 = reinterpret_cast<const float4*>(o1)[i];
  float4 v2 = reinterpret_cast<const float4*>(o2)[i];
  float4 A1 = reinterpret_cast<const float4*>(params)[c4];
  float4 B1 = reinterpret_cast<const float4*>(params + 96)[c4];
  float4 A2 = reinterpret_cast<const float4*>(params + 192)[c4];
  float4 B2 = reinterpret_cast<const float4*>(params + 288)[c4];
  float4 o;
  o.x = A1.x * v1.x + B1.x + A2.x * v2.x + B2.x;
  o.y = A1.y * v1.y + B1.y + A2.y * v2.y + B2.y;
  o.z = A1.z * v1.z + B1.z + A2.z * v2.z + B2.z;
  o.w = A1.w * v1.w + B1.w + A2.w * v2.w + B2.w;
  o.x = o.x > 0.0f ? o.x : 0.01f * o.x;
  o.y = o.y > 0.0f ? o.y : 0.01f * o.y;
  o.z = o.z > 0.0f ? o.z : 0.01f * o.z;
  o.w = o.w > 0.0f ? o.w : 0.01f * o.w;
  reinterpret_cast<float4*>(out)[i] = o;
}

extern "C" void kernel_launch(void* const* d_in, const int* in_sizes, int n_in,
                              void* d_out, int out_size, void* d_ws, size_t ws_size,
                              hipStream_t stream) {
  const float* x       = (const float*)d_in[0];
  const int*   ei      = (const int*)d_in[1];      // [2, E]: src then dst
  const float* W_self1 = (const float*)d_in[2];
  const float* W_neigh1= (const float*)d_in[3];
  const float* W_pool  = (const float*)d_in[4];
  const float* b_pool  = (const float*)d_in[5];
  const float* W_self2 = (const float*)d_in[6];
  const float* W_neigh2= (const float*)d_in[7];
  const float* g1      = (const float*)d_in[8];
  const float* beta1   = (const float*)d_in[9];
  const float* g2      = (const float*)d_in[10];
  const float* beta2   = (const float*)d_in[11];
  float* out = (float*)d_out;

  float* ws = (float*)d_ws;
  int*   deg       = (int*)(ws + OFF_DEG);
  int*   row_start = (int*)(ws + OFF_ROWSTART);
  int*   cursor    = (int*)(ws + OFF_CURSOR);
  int*   bsum      = (int*)(ws + OFF_BSUM);
  float* stats     = ws + OFF_STATS;
  float* params    = ws + OFF_PARAMS;
  int*   csr       = (int*)(ws + OFF_CSR);
  float* aggmean   = ws + OFF_AGGMEAN;   // becomes o1
  float* aggmax    = ws + OFF_AGGMAX;    // becomes o2
  float* hp        = ws + OFF_HP;

  const int* src = ei;
  const int* dst = ei + NE;

  hipMemsetAsync(deg, 0, NN * sizeof(int), stream);
  hipMemsetAsync(stats, 0, 384 * sizeof(float), stream);

  // CSR build
  deg_kernel<<<(NE + 255) / 256, 256, 0, stream>>>(dst, deg);
  scan_sum_kernel<<<SCAN_BLOCKS, 256, 0, stream>>>(deg, bsum);
  scan_bsum_kernel<<<1, 128, 0, stream>>>(bsum, row_start);
  scan_final_kernel<<<SCAN_BLOCKS, 256, 0, stream>>>(deg, bsum, row_start, cursor);
  fill_csr_kernel<<<(NE + 255) / 256, 256, 0, stream>>>(src, dst, cursor, csr);

  // hp = relu(x @ W_pool + b)
  hp_kernel<<<NN / 32, 256, 0, stream>>>(x, W_pool, b_pool, hp);

  // fused gather (mean of x, max of hp)
  gather_kernel<<<NN / 32, 256, 0, stream>>>(x, hp, row_start, csr, aggmean, aggmax);

  // o1 = x@W_self1 + aggmean@W_neigh1   (in place over aggmean)
  gemm_o_kernel<<<NN / 32, 256, 0, stream>>>(x, aggmean, W_self1, W_neigh1);
  // o2 = x@W_self2 + aggmax@W_neigh2    (in place over aggmax)
  gemm_o_kernel<<<NN / 32, 256, 0, stream>>>(x, aggmax, W_self2, W_neigh2);

  // BN stats, fold, final combine
  stats_kernel<<<512, 256, 0, stream>>>(aggmean, aggmax, stats);
  finalize_kernel<<<1, 128, 0, stream>>>(stats, g1, beta1, g2, beta2, params);
  final_kernel<<<(NN * 24 + 255) / 256, 256, 0, stream>>>(aggmean, aggmax, params, out);
}

// Round 4
// 338.330 us; speedup vs baseline: 6.4902x; 1.6307x over previous
//
#include <hip/hip_runtime.h>

#define NN 100000
#define NE 800000
#define DD 96
#define NROWPAD 100032
#define NBLK 1563              // NROWPAD / 64
#define SCAN_BLOCKS 100
#define SCAN_CHUNK 1000

typedef __attribute__((ext_vector_type(8))) short bf16x8;
typedef __attribute__((ext_vector_type(4))) float f32x4;
typedef unsigned short u16;
typedef unsigned int u32;

#define MFMA16 __builtin_amdgcn_mfma_f32_16x16x32_bf16

// workspace layout (4-byte element offsets; all 16B-aligned where vectors load)
#define OFF_DEG      0u          // NN ints
#define OFF_ROWSTART 100000u     // NN+1 ints
#define OFF_CURSOR   200004u     // NN ints
#define OFF_BSUM     300004u     // 128 ints
#define OFF_STATS    300132u     // 384 floats
#define OFF_PARAMS   300516u     // 384 floats
#define OFF_WT       300900u     // 5*9216 bf16 = 23040 floats (Ws1,Wn1,Ws2,Wn2,Wp transposed)
#define OFF_CSR      323940u     // NE ints
#define OFF_XBF      1123940u    // NROWPAD*96 bf16 = 4801536 floats
#define OFF_HMBF     5925476u    // NROWPAD*96 bf16
#define OFF_HXBF     10727012u   // NROWPAD*96 bf16
#define OFF_HPBF     15528548u   // NROWPAD*96 bf16
// top: 20330084 floats = 81.3 MB

__device__ __forceinline__ u16 f2b(float f) {           // fp32 -> bf16 RNE
  u32 u = __float_as_uint(f);
  u += 0x7FFFu + ((u >> 16) & 1u);
  return (u16)(u >> 16);
}
__device__ __forceinline__ float b2f(short h) {         // bf16 -> fp32 exact
  return __uint_as_float(((u32)(u16)h) << 16);
}

// ---------------- weight prep: transpose + bf16 (5 matrices) ----------------
__global__ void wprep_kernel(const float* __restrict__ Ws1, const float* __restrict__ Wn1,
                             const float* __restrict__ Ws2, const float* __restrict__ Wn2,
                             const float* __restrict__ Wp, u16* __restrict__ wt) {
  int idx = blockIdx.x * 256 + threadIdx.x;
  if (idx >= 5 * 9216) return;
  int m = idx / 9216, r = idx % 9216;
  int k = r / 96, c = r % 96;
  const float* W = (m == 0) ? Ws1 : (m == 1) ? Wn1 : (m == 2) ? Ws2 : (m == 3) ? Wn2 : Wp;
  wt[m * 9216 + c * 96 + k] = f2b(W[k * 96 + c]);
}

// ---------------- x -> bf16 ----------------
__global__ void cvt_kernel(const float* __restrict__ x, u16* __restrict__ xbf) {
  int i = blockIdx.x * 256 + threadIdx.x;  // one 8-elem chunk
  if (i >= NN * 12) return;
  float4 a = reinterpret_cast<const float4*>(x)[i * 2];
  float4 b = reinterpret_cast<const float4*>(x)[i * 2 + 1];
  bf16x8 v;
  v[0] = (short)f2b(a.x); v[1] = (short)f2b(a.y); v[2] = (short)f2b(a.z); v[3] = (short)f2b(a.w);
  v[4] = (short)f2b(b.x); v[5] = (short)f2b(b.y); v[6] = (short)f2b(b.z); v[7] = (short)f2b(b.w);
  reinterpret_cast<bf16x8*>(xbf)[i] = v;
}

// ---------------- degree histogram ----------------
__global__ void deg_kernel(const int* __restrict__ dst, int* __restrict__ deg) {
  int e = blockIdx.x * blockDim.x + threadIdx.x;
  if (e >= NE) return;
  atomicAdd(&deg[dst[e]], 1);
}

// ---------------- scan phase 1 ----------------
__global__ void scan_sum_kernel(const int* __restrict__ deg, int* __restrict__ bsum) {
  __shared__ int red[256];
  int t = threadIdx.x;
  int base = blockIdx.x * SCAN_CHUNK;
  int s = 0;
  for (int i = t; i < SCAN_CHUNK; i += 256) s += deg[base + i];
  red[t] = s;
  __syncthreads();
  for (int off = 128; off > 0; off >>= 1) {
    if (t < off) red[t] += red[t + off];
    __syncthreads();
  }
  if (t == 0) bsum[blockIdx.x] = red[0];
}

// ---------------- scan phase 2 ----------------
__global__ void scan_bsum_kernel(int* __restrict__ bsum, int* __restrict__ row_start) {
  __shared__ int sm[128];
  int t = threadIdx.x;
  int v = (t < SCAN_BLOCKS) ? bsum[t] : 0;
  sm[t] = v;
  __syncthreads();
  for (int off = 1; off < 128; off <<= 1) {
    int u = 0;
    if (t >= off) u = sm[t - off];
    __syncthreads();
    if (t >= off) sm[t] += u;
    __syncthreads();
  }
  if (t < SCAN_BLOCKS) bsum[t] = sm[t] - v;
  if (t == SCAN_BLOCKS - 1) row_start[NN] = sm[t];
}

// ---------------- scan phase 3 ----------------
__global__ void scan_final_kernel(const int* __restrict__ deg,
                                  const int* __restrict__ bsum,
                                  int* __restrict__ row_start,
                                  int* __restrict__ cursor) {
  __shared__ int sm[256];
  int t = threadIdx.x;
  int base = blockIdx.x * SCAN_CHUNK + t * 4;
  int4 d = {0, 0, 0, 0};
  if (t < 250) d = *reinterpret_cast<const int4*>(deg + base);
  int tot = d.x + d.y + d.z + d.w;
  sm[t] = tot;
  __syncthreads();
  for (int off = 1; off < 256; off <<= 1) {
    int u = 0;
    if (t >= off) u = sm[t - off];
    __syncthreads();
    if (t >= off) sm[t] += u;
    __syncthreads();
  }
  if (t < 250) {
    int run = bsum[blockIdx.x] + sm[t] - tot;
    int4 rs;
    rs.x = run;
    rs.y = run + d.x;
    rs.z = run + d.x + d.y;
    rs.w = run + d.x + d.y + d.z;
    *reinterpret_cast<int4*>(row_start + base) = rs;
    *reinterpret_cast<int4*>(cursor + base) = rs;
  }
}

// ---------------- fill CSR ----------------
__global__ void fill_csr_kernel(const int* __restrict__ src,
                                const int* __restrict__ dst,
                                int* __restrict__ cursor,
                                int* __restrict__ csr) {
  int e = blockIdx.x * blockDim.x + threadIdx.x;
  if (e >= NE) return;
  int pos = atomicAdd(&cursor[dst[e]], 1);
  csr[pos] = src[e];
}

// ---------------- hp = relu(x @ Wp + bp) via MFMA, bf16 out ----------------
__global__ __launch_bounds__(256) void hp_gemm_kernel(const u16* __restrict__ xbf,
                                                      const u16* __restrict__ wt,
                                                      const float* __restrict__ bp,
                                                      u16* __restrict__ hpbf) {
  int t = threadIdx.x;
  int w = t >> 6, lane = t & 63;
  int i = lane & 15, g = lane >> 4;
  int row_base = blockIdx.x * 64 + w * 16;
  size_t arow = (size_t)(row_base + i) * 12;   // 12 bf16x8 chunks per row
  bf16x8 ax[3];
#pragma unroll
  for (int kb = 0; kb < 3; ++kb) ax[kb] = reinterpret_cast<const bf16x8*>(xbf)[arow + kb * 4 + g];
  const bf16x8* wb = reinterpret_cast<const bf16x8*>(wt + 4 * 9216);  // Wp^T
  for (int nt = 0; nt < 6; ++nt) {
    f32x4 acc = {0.f, 0.f, 0.f, 0.f};
    int bch = (nt * 16 + i) * 12;
#pragma unroll
    for (int kb = 0; kb < 3; ++kb)
      acc = MFMA16(ax[kb], wb[bch + kb * 4 + g], acc, 0, 0, 0);
    int col = nt * 16 + i;
    float bias = bp[col];
#pragma unroll
    for (int r = 0; r < 4; ++r) {
      int grow = row_base + g * 4 + r;
      if (grow < NN)
        hpbf[(size_t)grow * 96 + col] = f2b(fmaxf(acc[r] + bias, 0.0f));
    }
  }
}

// ---------------- fused gather (bf16 in/out): mean x[nbr], max hp[nbr] ----------------
__global__ __launch_bounds__(256) void gather_kernel(const u16* __restrict__ xbf,
                                                     const u16* __restrict__ hpbf,
                                                     const int* __restrict__ row_start,
                                                     const int* __restrict__ csr,
                                                     u16* __restrict__ hmbf,
                                                     u16* __restrict__ hxbf) {
  int t = threadIdx.x;
  int node = blockIdx.x * 64 + (t >> 2);
  if (node >= NN) return;
  int ln = t & 3;                        // 4 lanes/node, 3 chunks each
  int beg = row_start[node], end = row_start[node + 1];
  float s[3][8], mx[3][8];
#pragma unroll
  for (int c = 0; c < 3; ++c)
#pragma unroll
    for (int e8 = 0; e8 < 8; ++e8) { s[c][e8] = 0.f; mx[c][e8] = 0.f; }
  for (int e = beg; e < end; ++e) {
    int srow = csr[e];
    size_t base = (size_t)srow * 12;
#pragma unroll
    for (int c = 0; c < 3; ++c) {
      bf16x8 xv = reinterpret_cast<const bf16x8*>(xbf)[base + ln + c * 4];
      bf16x8 hv = reinterpret_cast<const bf16x8*>(hpbf)[base + ln + c * 4];
#pragma unroll
      for (int e8 = 0; e8 < 8; ++e8) {
        s[c][e8] += b2f(xv[e8]);
        mx[c][e8] = fmaxf(mx[c][e8], b2f(hv[e8]));
      }
    }
  }
  float inv = (end > beg) ? 1.0f / (float)(end - beg) : 0.0f;
  size_t obase = (size_t)node * 12;
#pragma unroll
  for (int c = 0; c < 3; ++c) {
    bf16x8 vm, vx;
#pragma unroll
    for (int e8 = 0; e8 < 8; ++e8) {
      vm[e8] = (short)f2b(s[c][e8] * inv);
      vx[e8] = (short)f2b(mx[c][e8]);
    }
    reinterpret_cast<bf16x8*>(hmbf)[obase + ln + c * 4] = vm;
    reinterpret_cast<bf16x8*>(hxbf)[obase + ln + c * 4] = vx;
  }
}

// ---------------- dual GEMM: o1 = x@Ws1 + hm@Wn1, o2 = x@Ws2 + hx@Wn2 ----------------
// mode 0: accumulate BN stats only.  mode 1: apply folded BN + add + leakyReLU, write out.
__global__ __launch_bounds__(256) void dualgemm_kernel(const u16* __restrict__ xbf,
                                                       const u16* __restrict__ hmbf,
                                                       const u16* __restrict__ hxbf,
                                                       const u16* __restrict__ wt,
                                                       float* __restrict__ stats,
                                                       const float* __restrict__ params,
                                                       float* __restrict__ out,
                                                       int mode) {
  __shared__ float smst[384];
  int t = threadIdx.x;
  if (mode == 0) {
    for (int j = t; j < 384; j += 256) smst[j] = 0.f;
    __syncthreads();
  }
  int w = t >> 6, lane = t & 63;
  int i = lane & 15, g = lane >> 4;
  int row_base = blockIdx.x * 64 + w * 16;
  size_t arow = (size_t)(row_base + i) * 12;
  bf16x8 ax[3], am[3], ah[3];
#pragma unroll
  for (int kb = 0; kb < 3; ++kb) {
    ax[kb] = reinterpret_cast<const bf16x8*>(xbf)[arow + kb * 4 + g];
    am[kb] = reinterpret_cast<const bf16x8*>(hmbf)[arow + kb * 4 + g];
    ah[kb] = reinterpret_cast<const bf16x8*>(hxbf)[arow + kb * 4 + g];
  }
  const bf16x8* w0 = reinterpret_cast<const bf16x8*>(wt);             // Ws1^T
  const bf16x8* w1 = reinterpret_cast<const bf16x8*>(wt + 9216);      // Wn1^T
  const bf16x8* w2 = reinterpret_cast<const bf16x8*>(wt + 2 * 9216);  // Ws2^T
  const bf16x8* w3 = reinterpret_cast<const bf16x8*>(wt + 3 * 9216);  // Wn2^T
  for (int nt = 0; nt < 6; ++nt) {
    f32x4 a1 = {0.f, 0.f, 0.f, 0.f}, a2 = {0.f, 0.f, 0.f, 0.f};
    int bch = (nt * 16 + i) * 12;
#pragma unroll
    for (int kb = 0; kb < 3; ++kb) {
      int bc = bch + kb * 4 + g;
      a1 = MFMA16(ax[kb], w0[bc], a1, 0, 0, 0);
      a1 = MFMA16(am[kb], w1[bc], a1, 0, 0, 0);
      a2 = MFMA16(ax[kb], w2[bc], a2, 0, 0, 0);
      a2 = MFMA16(ah[kb], w3[bc], a2, 0, 0, 0);
    }
    int col = nt * 16 + i;
    if (mode == 0) {
      float s1 = 0, q1 = 0, s2 = 0, q2 = 0;
#pragma unroll
      for (int r = 0; r < 4; ++r) {
        int grow = row_base + g * 4 + r;
        if (grow < NN) {
          float v = a1[r], u = a2[r];
          s1 += v; q1 += v * v; s2 += u; q2 += u * u;
        }
      }
      s1 += __shfl_xor(s1, 16); q1 += __shfl_xor(q1, 16);
      s2 += __shfl_xor(s2, 16); q2 += __shfl_xor(q2, 16);
      s1 += __shfl_xor(s1, 32); q1 += __shfl_xor(q1, 32);
      s2 += __shfl_xor(s2, 32); q2 += __shfl_xor(q2, 32);
      if (g == 0) {
        atomicAdd(&smst[col], s1);
        atomicAdd(&smst[96 + col], q1);
        atomicAdd(&smst[192 + col], s2);
        atomicAdd(&smst[288 + col], q2);
      }
    } else {
      float p1 = params[col], c1 = params[96 + col];
      float p2 = params[192 + col], c2 = params[288 + col];
#pragma unroll
      for (int r = 0; r < 4; ++r) {
        int grow = row_base + g * 4 + r;
        if (grow < NN) {
          float v = p1 * a1[r] + c1 + p2 * a2[r] + c2;
          v = v > 0.f ? v : 0.01f * v;
          out[(size_t)grow * 96 + col] = v;
        }
      }
    }
  }
  if (mode == 0) {
    __syncthreads();
    for (int j = t; j < 384; j += 256) atomicAdd(&stats[j], smst[j]);
  }
}

// ---------------- fold BN into per-column affine ----------------
__global__ void finalize_kernel(const float* __restrict__ stats,
                                const float* __restrict__ g1, const float* __restrict__ beta1,
                                const float* __restrict__ g2, const float* __restrict__ beta2,
                                float* __restrict__ params) {
  int c = threadIdx.x;
  if (c >= 96) return;
  const float inv_n = 1.0f / NN;
  float mu1 = stats[c] * inv_n;
  float var1 = fmaxf(stats[96 + c] * inv_n - mu1 * mu1, 0.0f);
  float is1 = rsqrtf(var1 + 1e-5f);
  float a1 = g1[c] * is1;
  params[c] = a1;
  params[96 + c] = beta1[c] - a1 * mu1;
  float mu2 = stats[192 + c] * inv_n;
  float var2 = fmaxf(stats[288 + c] * inv_n - mu2 * mu2, 0.0f);
  float is2 = rsqrtf(var2 + 1e-5f);
  float a2 = g2[c] * is2;
  params[192 + c] = a2;
  params[288 + c] = beta2[c] - a2 * mu2;
}

extern "C" void kernel_launch(void* const* d_in, const int* in_sizes, int n_in,
                              void* d_out, int out_size, void* d_ws, size_t ws_size,
                              hipStream_t stream) {
  const float* x       = (const float*)d_in[0];
  const int*   ei      = (const int*)d_in[1];
  const float* W_self1 = (const float*)d_in[2];
  const float* W_neigh1= (const float*)d_in[3];
  const float* W_pool  = (const float*)d_in[4];
  const float* b_pool  = (const float*)d_in[5];
  const float* W_self2 = (const float*)d_in[6];
  const float* W_neigh2= (const float*)d_in[7];
  const float* g1      = (const float*)d_in[8];
  const float* beta1   = (const float*)d_in[9];
  const float* g2      = (const float*)d_in[10];
  const float* beta2   = (const float*)d_in[11];
  float* out = (float*)d_out;

  float* ws = (float*)d_ws;
  int*   deg       = (int*)(ws + OFF_DEG);
  int*   row_start = (int*)(ws + OFF_ROWSTART);
  int*   cursor    = (int*)(ws + OFF_CURSOR);
  int*   bsum      = (int*)(ws + OFF_BSUM);
  float* stats     = ws + OFF_STATS;
  float* params    = ws + OFF_PARAMS;
  u16*   wt        = (u16*)(ws + OFF_WT);
  int*   csr       = (int*)(ws + OFF_CSR);
  u16*   xbf       = (u16*)(ws + OFF_XBF);
  u16*   hmbf      = (u16*)(ws + OFF_HMBF);
  u16*   hxbf      = (u16*)(ws + OFF_HXBF);
  u16*   hpbf      = (u16*)(ws + OFF_HPBF);

  const int* src = ei;
  const int* dst = ei + NE;

  hipMemsetAsync(deg, 0, NN * sizeof(int), stream);
  hipMemsetAsync(stats, 0, 384 * sizeof(float), stream);

  // prep: weights + x in bf16
  wprep_kernel<<<(5 * 9216 + 255) / 256, 256, 0, stream>>>(W_self1, W_neigh1, W_self2,
                                                           W_neigh2, W_pool, wt);
  cvt_kernel<<<(NN * 12 + 255) / 256, 256, 0, stream>>>(x, xbf);

  // CSR build
  deg_kernel<<<(NE + 255) / 256, 256, 0, stream>>>(dst, deg);
  scan_sum_kernel<<<SCAN_BLOCKS, 256, 0, stream>>>(deg, bsum);
  scan_bsum_kernel<<<1, 128, 0, stream>>>(bsum, row_start);
  scan_final_kernel<<<SCAN_BLOCKS, 256, 0, stream>>>(deg, bsum, row_start, cursor);
  fill_csr_kernel<<<(NE + 255) / 256, 256, 0, stream>>>(src, dst, cursor, csr);

  // hp = relu(x @ Wp + bp) -> bf16
  hp_gemm_kernel<<<NBLK, 256, 0, stream>>>(xbf, wt, b_pool, hpbf);

  // gather: mean(x) and max(hp) over neighbors -> bf16
  gather_kernel<<<NBLK, 256, 0, stream>>>(xbf, hpbf, row_start, csr, hmbf, hxbf);

  // pass 1: BN stats; fold; pass 2: fused output
  dualgemm_kernel<<<NBLK, 256, 0, stream>>>(xbf, hmbf, hxbf, wt, stats, params, out, 0);
  finalize_kernel<<<1, 128, 0, stream>>>(stats, g1, beta1, g2, beta2, params);
  dualgemm_kernel<<<NBLK, 256, 0, stream>>>(xbf, hmbf, hxbf, wt, stats, params, out, 1);
}

// Round 5
// 287.992 us; speedup vs baseline: 7.6246x; 1.1748x over previous
//
#include <hip/hip_runtime.h>

#define NN 100000
#define NE 800000
#define DD 96
#define NROWPAD 100096            // 782 * 128
#define GBLK 782                  // GEMM blocks (128 rows each)
#define SCAN_BLOCKS 100
#define SCAN_CHUNK 1000

typedef __attribute__((ext_vector_type(8))) short bf16x8;
typedef __attribute__((ext_vector_type(4))) float f32x4;
typedef unsigned short u16;
typedef unsigned int u32;

#define MFMA16 __builtin_amdgcn_mfma_f32_16x16x32_bf16

// workspace layout (4-byte element offsets)
#define OFF_DEG      0u          // NN ints
#define OFF_ROWSTART 100000u     // NN+1 ints
#define OFF_CURSOR   200004u     // NN ints
#define OFF_BSUM     300004u     // 128 ints
#define OFF_STATS    300132u     // 384 floats
#define OFF_PARAMS   300516u     // 384 floats
#define OFF_WT       300900u     // 5*9216 bf16 (Ws1,Wn1,Ws2,Wn2,Wp transposed)
#define OFF_CSR      323940u     // NE ints
#define ROWF         4804608u    // NROWPAD*96 bf16 in float units
#define OFF_XBF      1123940u
#define OFF_HMBF     (OFF_XBF + ROWF)
#define OFF_HXBF     (OFF_HMBF + ROWF)
#define OFF_HPBF     (OFF_HXBF + ROWF)
// top ≈ 20.3M floats ≈ 81.4 MB

__device__ __forceinline__ u16 f2b(float f) {
  u32 u = __float_as_uint(f);
  u += 0x7FFFu + ((u >> 16) & 1u);
  return (u16)(u >> 16);
}
__device__ __forceinline__ float b2f(short h) {
  return __uint_as_float(((u32)(u16)h) << 16);
}

// ---------------- weight prep: transpose + bf16 ----------------
__global__ void wprep_kernel(const float* __restrict__ Ws1, const float* __restrict__ Wn1,
                             const float* __restrict__ Ws2, const float* __restrict__ Wn2,
                             const float* __restrict__ Wp, u16* __restrict__ wt) {
  int idx = blockIdx.x * 256 + threadIdx.x;
  if (idx >= 5 * 9216) return;
  int m = idx / 9216, r = idx % 9216;
  int k = r / 96, c = r % 96;
  const float* W = (m == 0) ? Ws1 : (m == 1) ? Wn1 : (m == 2) ? Ws2 : (m == 3) ? Wn2 : Wp;
  wt[m * 9216 + c * 96 + k] = f2b(W[k * 96 + c]);
}

// ---------------- x -> bf16 ----------------
__global__ void cvt_kernel(const float* __restrict__ x, u16* __restrict__ xbf) {
  int i = blockIdx.x * 256 + threadIdx.x;
  if (i >= NN * 12) return;
  float4 a = reinterpret_cast<const float4*>(x)[i * 2];
  float4 b = reinterpret_cast<const float4*>(x)[i * 2 + 1];
  bf16x8 v;
  v[0] = (short)f2b(a.x); v[1] = (short)f2b(a.y); v[2] = (short)f2b(a.z); v[3] = (short)f2b(a.w);
  v[4] = (short)f2b(b.x); v[5] = (short)f2b(b.y); v[6] = (short)f2b(b.z); v[7] = (short)f2b(b.w);
  reinterpret_cast<bf16x8*>(xbf)[i] = v;
}

// ---------------- degree histogram ----------------
__global__ void deg_kernel(const int* __restrict__ dst, int* __restrict__ deg) {
  int e = blockIdx.x * blockDim.x + threadIdx.x;
  if (e >= NE) return;
  atomicAdd(&deg[dst[e]], 1);
}

// ---------------- scan phase 1 ----------------
__global__ void scan_sum_kernel(const int* __restrict__ deg, int* __restrict__ bsum) {
  __shared__ int red[256];
  int t = threadIdx.x;
  int base = blockIdx.x * SCAN_CHUNK;
  int s = 0;
  for (int i = t; i < SCAN_CHUNK; i += 256) s += deg[base + i];
  red[t] = s;
  __syncthreads();
  for (int off = 128; off > 0; off >>= 1) {
    if (t < off) red[t] += red[t + off];
    __syncthreads();
  }
  if (t == 0) bsum[blockIdx.x] = red[0];
}

// ---------------- scan phase 2 ----------------
__global__ void scan_bsum_kernel(int* __restrict__ bsum, int* __restrict__ row_start) {
  __shared__ int sm[128];
  int t = threadIdx.x;
  int v = (t < SCAN_BLOCKS) ? bsum[t] : 0;
  sm[t] = v;
  __syncthreads();
  for (int off = 1; off < 128; off <<= 1) {
    int u = 0;
    if (t >= off) u = sm[t - off];
    __syncthreads();
    if (t >= off) sm[t] += u;
    __syncthreads();
  }
  if (t < SCAN_BLOCKS) bsum[t] = sm[t] - v;
  if (t == SCAN_BLOCKS - 1) row_start[NN] = sm[t];
}

// ---------------- scan phase 3 ----------------
__global__ void scan_final_kernel(const int* __restrict__ deg,
                                  const int* __restrict__ bsum,
                                  int* __restrict__ row_start,
                                  int* __restrict__ cursor) {
  __shared__ int sm[256];
  int t = threadIdx.x;
  int base = blockIdx.x * SCAN_CHUNK + t * 4;
  int4 d = {0, 0, 0, 0};
  if (t < 250) d = *reinterpret_cast<const int4*>(deg + base);
  int tot = d.x + d.y + d.z + d.w;
  sm[t] = tot;
  __syncthreads();
  for (int off = 1; off < 256; off <<= 1) {
    int u = 0;
    if (t >= off) u = sm[t - off];
    __syncthreads();
    if (t >= off) sm[t] += u;
    __syncthreads();
  }
  if (t < 250) {
    int run = bsum[blockIdx.x] + sm[t] - tot;
    int4 rs;
    rs.x = run;
    rs.y = run + d.x;
    rs.z = run + d.x + d.y;
    rs.w = run + d.x + d.y + d.z;
    *reinterpret_cast<int4*>(row_start + base) = rs;
    *reinterpret_cast<int4*>(cursor + base) = rs;
  }
}

// ---------------- fill CSR ----------------
__global__ void fill_csr_kernel(const int* __restrict__ src,
                                const int* __restrict__ dst,
                                int* __restrict__ cursor,
                                int* __restrict__ csr) {
  int e = blockIdx.x * blockDim.x + threadIdx.x;
  if (e >= NE) return;
  int pos = atomicAdd(&cursor[dst[e]], 1);
  csr[pos] = src[e];
}

// ---------------- hp = relu(x @ Wp + bp), Wp in LDS ----------------
__global__ __launch_bounds__(512) void hp_gemm_kernel(const u16* __restrict__ xbf,
                                                      const u16* __restrict__ wt,
                                                      const float* __restrict__ bp,
                                                      u16* __restrict__ hpbf) {
  __shared__ bf16x8 wl[1152];   // Wp^T: 96 cols x 96 k
  int t = threadIdx.x;
  const bf16x8* wg = reinterpret_cast<const bf16x8*>(wt + 4 * 9216);
  for (int j = t; j < 1152; j += 512) wl[j] = wg[j];
  __syncthreads();
  int w = t >> 6, lane = t & 63;
  int i = lane & 15, g = lane >> 4;
  int row_base = blockIdx.x * 128 + w * 16;
  size_t arow = (size_t)(row_base + i) * 12;
  bf16x8 ax[3];
#pragma unroll
  for (int kb = 0; kb < 3; ++kb) ax[kb] = reinterpret_cast<const bf16x8*>(xbf)[arow + kb * 4 + g];
  for (int nt = 0; nt < 6; ++nt) {
    f32x4 acc = {0.f, 0.f, 0.f, 0.f};
    int bch = (nt * 16 + i) * 12;
#pragma unroll
    for (int kb = 0; kb < 3; ++kb)
      acc = MFMA16(ax[kb], wl[bch + kb * 4 + g], acc, 0, 0, 0);
    int col = nt * 16 + i;
    float bias = bp[col];
#pragma unroll
    for (int r = 0; r < 4; ++r) {
      int grow = row_base + g * 4 + r;
      if (grow < NN)
        hpbf[(size_t)grow * 96 + col] = f2b(fmaxf(acc[r] + bias, 0.0f));
    }
  }
}

// ---------------- fused gather (bf16): mean x[nbr], max hp[nbr] ----------------
__global__ __launch_bounds__(256) void gather_kernel(const u16* __restrict__ xbf,
                                                     const u16* __restrict__ hpbf,
                                                     const int* __restrict__ row_start,
                                                     const int* __restrict__ csr,
                                                     u16* __restrict__ hmbf,
                                                     u16* __restrict__ hxbf) {
  int t = threadIdx.x;
  int node = blockIdx.x * 64 + (t >> 2);
  if (node >= NN) return;
  int ln = t & 3;
  int beg = row_start[node], end = row_start[node + 1];
  float s[3][8], mx[3][8];
#pragma unroll
  for (int c = 0; c < 3; ++c)
#pragma unroll
    for (int e8 = 0; e8 < 8; ++e8) { s[c][e8] = 0.f; mx[c][e8] = 0.f; }
  for (int e = beg; e < end; ++e) {
    int srow = csr[e];
    size_t base = (size_t)srow * 12;
#pragma unroll
    for (int c = 0; c < 3; ++c) {
      bf16x8 xv = reinterpret_cast<const bf16x8*>(xbf)[base + ln + c * 4];
      bf16x8 hv = reinterpret_cast<const bf16x8*>(hpbf)[base + ln + c * 4];
#pragma unroll
      for (int e8 = 0; e8 < 8; ++e8) {
        s[c][e8] += b2f(xv[e8]);
        mx[c][e8] = fmaxf(mx[c][e8], b2f(hv[e8]));
      }
    }
  }
  float inv = (end > beg) ? 1.0f / (float)(end - beg) : 0.0f;
  size_t obase = (size_t)node * 12;
#pragma unroll
  for (int c = 0; c < 3; ++c) {
    bf16x8 vm, vx;
#pragma unroll
    for (int e8 = 0; e8 < 8; ++e8) {
      vm[e8] = (short)f2b(s[c][e8] * inv);
      vx[e8] = (short)f2b(mx[c][e8]);
    }
    reinterpret_cast<bf16x8*>(hmbf)[obase + ln + c * 4] = vm;
    reinterpret_cast<bf16x8*>(hxbf)[obase + ln + c * 4] = vx;
  }
}

// ---------------- dual GEMM, all 4 weights in LDS ----------------
// mode 0: accumulate BN stats. mode 1: folded BN + add + leakyReLU -> out.
__global__ __launch_bounds__(512) void dualgemm_kernel(const u16* __restrict__ xbf,
                                                       const u16* __restrict__ hmbf,
                                                       const u16* __restrict__ hxbf,
                                                       const u16* __restrict__ wt,
                                                       float* __restrict__ stats,
                                                       const float* __restrict__ params,
                                                       float* __restrict__ out,
                                                       int mode) {
  __shared__ bf16x8 wl[4608];   // Ws1,Wn1,Ws2,Wn2 transposed
  __shared__ float smst[384];
  int t = threadIdx.x;
  const bf16x8* wg = reinterpret_cast<const bf16x8*>(wt);
  for (int j = t; j < 4608; j += 512) wl[j] = wg[j];
  if (mode == 0)
    for (int j = t; j < 384; j += 512) smst[j] = 0.f;
  __syncthreads();
  int w = t >> 6, lane = t & 63;
  int i = lane & 15, g = lane >> 4;
  int row_base = blockIdx.x * 128 + w * 16;
  size_t arow = (size_t)(row_base + i) * 12;
  bf16x8 ax[3], am[3], ah[3];
#pragma unroll
  for (int kb = 0; kb < 3; ++kb) {
    ax[kb] = reinterpret_cast<const bf16x8*>(xbf)[arow + kb * 4 + g];
    am[kb] = reinterpret_cast<const bf16x8*>(hmbf)[arow + kb * 4 + g];
    ah[kb] = reinterpret_cast<const bf16x8*>(hxbf)[arow + kb * 4 + g];
  }
  for (int nt = 0; nt < 6; ++nt) {
    f32x4 a1 = {0.f, 0.f, 0.f, 0.f}, a2 = {0.f, 0.f, 0.f, 0.f};
    int bch = (nt * 16 + i) * 12;
#pragma unroll
    for (int kb = 0; kb < 3; ++kb) {
      int bc = bch + kb * 4 + g;
      a1 = MFMA16(ax[kb], wl[bc], a1, 0, 0, 0);
      a1 = MFMA16(am[kb], wl[1152 + bc], a1, 0, 0, 0);
      a2 = MFMA16(ax[kb], wl[2304 + bc], a2, 0, 0, 0);
      a2 = MFMA16(ah[kb], wl[3456 + bc], a2, 0, 0, 0);
    }
    int col = nt * 16 + i;
    if (mode == 0) {
      float s1 = 0, q1 = 0, s2 = 0, q2 = 0;
#pragma unroll
      for (int r = 0; r < 4; ++r) {
        int grow = row_base + g * 4 + r;
        if (grow < NN) {
          float v = a1[r], u = a2[r];
          s1 += v; q1 += v * v; s2 += u; q2 += u * u;
        }
      }
      s1 += __shfl_xor(s1, 16); q1 += __shfl_xor(q1, 16);
      s2 += __shfl_xor(s2, 16); q2 += __shfl_xor(q2, 16);
      s1 += __shfl_xor(s1, 32); q1 += __shfl_xor(q1, 32);
      s2 += __shfl_xor(s2, 32); q2 += __shfl_xor(q2, 32);
      if (g == 0) {
        atomicAdd(&smst[col], s1);
        atomicAdd(&smst[96 + col], q1);
        atomicAdd(&smst[192 + col], s2);
        atomicAdd(&smst[288 + col], q2);
      }
    } else {
      float p1 = params[col], c1 = params[96 + col];
      float p2 = params[192 + col], c2 = params[288 + col];
#pragma unroll
      for (int r = 0; r < 4; ++r) {
        int grow = row_base + g * 4 + r;
        if (grow < NN) {
          float v = p1 * a1[r] + c1 + p2 * a2[r] + c2;
          v = v > 0.f ? v : 0.01f * v;
          out[(size_t)grow * 96 + col] = v;
        }
      }
    }
  }
  if (mode == 0) {
    __syncthreads();
    for (int j = t; j < 384; j += 512) atomicAdd(&stats[j], smst[j]);
  }
}

// ---------------- fold BN into per-column affine ----------------
__global__ void finalize_kernel(const float* __restrict__ stats,
                                const float* __restrict__ g1, const float* __restrict__ beta1,
                                const float* __restrict__ g2, const float* __restrict__ beta2,
                                float* __restrict__ params) {
  int c = threadIdx.x;
  if (c >= 96) return;
  const float inv_n = 1.0f / NN;
  float mu1 = stats[c] * inv_n;
  float var1 = fmaxf(stats[96 + c] * inv_n - mu1 * mu1, 0.0f);
  float is1 = rsqrtf(var1 + 1e-5f);
  float a1 = g1[c] * is1;
  params[c] = a1;
  params[96 + c] = beta1[c] - a1 * mu1;
  float mu2 = stats[192 + c] * inv_n;
  float var2 = fmaxf(stats[288 + c] * inv_n - mu2 * mu2, 0.0f);
  float is2 = rsqrtf(var2 + 1e-5f);
  float a2 = g2[c] * is2;
  params[192 + c] = a2;
  params[288 + c] = beta2[c] - a2 * mu2;
}

extern "C" void kernel_launch(void* const* d_in, const int* in_sizes, int n_in,
                              void* d_out, int out_size, void* d_ws, size_t ws_size,
                              hipStream_t stream) {
  const float* x       = (const float*)d_in[0];
  const int*   ei      = (const int*)d_in[1];
  const float* W_self1 = (const float*)d_in[2];
  const float* W_neigh1= (const float*)d_in[3];
  const float* W_pool  = (const float*)d_in[4];
  const float* b_pool  = (const float*)d_in[5];
  const float* W_self2 = (const float*)d_in[6];
  const float* W_neigh2= (const float*)d_in[7];
  const float* g1      = (const float*)d_in[8];
  const float* beta1   = (const float*)d_in[9];
  const float* g2      = (const float*)d_in[10];
  const float* beta2   = (const float*)d_in[11];
  float* out = (float*)d_out;

  float* ws = (float*)d_ws;
  int*   deg       = (int*)(ws + OFF_DEG);
  int*   row_start = (int*)(ws + OFF_ROWSTART);
  int*   cursor    = (int*)(ws + OFF_CURSOR);
  int*   bsum      = (int*)(ws + OFF_BSUM);
  float* stats     = ws + OFF_STATS;
  float* params    = ws + OFF_PARAMS;
  u16*   wt        = (u16*)(ws + OFF_WT);
  int*   csr       = (int*)(ws + OFF_CSR);
  u16*   xbf       = (u16*)(ws + OFF_XBF);
  u16*   hmbf      = (u16*)(ws + OFF_HMBF);
  u16*   hxbf      = (u16*)(ws + OFF_HXBF);
  u16*   hpbf      = (u16*)(ws + OFF_HPBF);

  const int* src = ei;
  const int* dst = ei + NE;

  hipMemsetAsync(deg, 0, NN * sizeof(int), stream);
  hipMemsetAsync(stats, 0, 384 * sizeof(float), stream);

  wprep_kernel<<<(5 * 9216 + 255) / 256, 256, 0, stream>>>(W_self1, W_neigh1, W_self2,
                                                           W_neigh2, W_pool, wt);
  cvt_kernel<<<(NN * 12 + 255) / 256, 256, 0, stream>>>(x, xbf);

  deg_kernel<<<(NE + 255) / 256, 256, 0, stream>>>(dst, deg);
  scan_sum_kernel<<<SCAN_BLOCKS, 256, 0, stream>>>(deg, bsum);
  scan_bsum_kernel<<<1, 128, 0, stream>>>(bsum, row_start);
  scan_final_kernel<<<SCAN_BLOCKS, 256, 0, stream>>>(deg, bsum, row_start, cursor);
  fill_csr_kernel<<<(NE + 255) / 256, 256, 0, stream>>>(src, dst, cursor, csr);

  hp_gemm_kernel<<<GBLK, 512, 0, stream>>>(xbf, wt, b_pool, hpbf);

  gather_kernel<<<(NN + 63) / 64, 256, 0, stream>>>(xbf, hpbf, row_start, csr, hmbf, hxbf);

  dualgemm_kernel<<<GBLK, 512, 0, stream>>>(xbf, hmbf, hxbf, wt, stats, params, out, 0);
  finalize_kernel<<<1, 128, 0, stream>>>(stats, g1, beta1, g2, beta2, params);
  dualgemm_kernel<<<GBLK, 512, 0, stream>>>(xbf, hmbf, hxbf, wt, stats, params, out, 1);
}

// Round 6
// 278.016 us; speedup vs baseline: 7.8982x; 1.0359x over previous
//
#include <hip/hip_runtime.h>

#define NN 100000
#define NE 800000
#define DD 96
#define NROWPAD 100096            // 782 * 128
#define GBLK 782                  // GEMM blocks (128 rows each)
#define SCAN_BLOCKS 100
#define SCAN_CHUNK 1000

typedef __attribute__((ext_vector_type(8))) short bf16x8;
typedef __attribute__((ext_vector_type(4))) float f32x4;
typedef unsigned short u16;
typedef unsigned int u32;

#define MFMA16 __builtin_amdgcn_mfma_f32_16x16x32_bf16

// workspace layout (4-byte element offsets)
#define OFF_DEG      0u          // NN ints
#define OFF_ROWSTART 100000u     // NN+1 ints
#define OFF_CURSOR   200004u     // NN ints
#define OFF_BSUM     300004u     // 128 ints
#define OFF_STATS    300132u     // 384 floats
#define OFF_PARAMS   300516u     // 384 floats
#define OFF_WT       300900u     // 5*9216 bf16 (Ws1,Wn1,Ws2,Wn2,Wp transposed)
#define OFF_CSR      323940u     // NE ints
#define OFF_XH       1123940u    // NROWPAD * 96 floats (combined x|hp bf16 rows, 384B each)
#define OFF_HMBF     10733156u   // NROWPAD * 48 floats (bf16 rows, 192B)
#define OFF_HXBF     15537764u   // NROWPAD * 48 floats
// top = 20342372 floats ≈ 81.4 MB

__device__ __forceinline__ u16 f2b(float f) {
  u32 u = __float_as_uint(f);
  u += 0x7FFFu + ((u >> 16) & 1u);
  return (u16)(u >> 16);
}
__device__ __forceinline__ float b2f(short h) {
  return __uint_as_float(((u32)(u16)h) << 16);
}

// ---------------- weight prep: transpose + bf16 ----------------
__global__ void wprep_kernel(const float* __restrict__ Ws1, const float* __restrict__ Wn1,
                             const float* __restrict__ Ws2, const float* __restrict__ Wn2,
                             const float* __restrict__ Wp, u16* __restrict__ wt) {
  int idx = blockIdx.x * 256 + threadIdx.x;
  if (idx >= 5 * 9216) return;
  int m = idx / 9216, r = idx % 9216;
  int k = r / 96, c = r % 96;
  const float* W = (m == 0) ? Ws1 : (m == 1) ? Wn1 : (m == 2) ? Ws2 : (m == 3) ? Wn2 : Wp;
  wt[m * 9216 + c * 96 + k] = f2b(W[k * 96 + c]);
}

// ---------------- degree histogram ----------------
__global__ void deg_kernel(const int* __restrict__ dst, int* __restrict__ deg) {
  int e = blockIdx.x * blockDim.x + threadIdx.x;
  if (e >= NE) return;
  atomicAdd(&deg[dst[e]], 1);
}

// ---------------- scan phase 1 ----------------
__global__ void scan_sum_kernel(const int* __restrict__ deg, int* __restrict__ bsum) {
  __shared__ int red[256];
  int t = threadIdx.x;
  int base = blockIdx.x * SCAN_CHUNK;
  int s = 0;
  for (int i = t; i < SCAN_CHUNK; i += 256) s += deg[base + i];
  red[t] = s;
  __syncthreads();
  for (int off = 128; off > 0; off >>= 1) {
    if (t < off) red[t] += red[t + off];
    __syncthreads();
  }
  if (t == 0) bsum[blockIdx.x] = red[0];
}

// ---------------- scan phase 2 ----------------
__global__ void scan_bsum_kernel(int* __restrict__ bsum, int* __restrict__ row_start) {
  __shared__ int sm[128];
  int t = threadIdx.x;
  int v = (t < SCAN_BLOCKS) ? bsum[t] : 0;
  sm[t] = v;
  __syncthreads();
  for (int off = 1; off < 128; off <<= 1) {
    int u = 0;
    if (t >= off) u = sm[t - off];
    __syncthreads();
    if (t >= off) sm[t] += u;
    __syncthreads();
  }
  if (t < SCAN_BLOCKS) bsum[t] = sm[t] - v;
  if (t == SCAN_BLOCKS - 1) row_start[NN] = sm[t];
}

// ---------------- scan phase 3 ----------------
__global__ void scan_final_kernel(const int* __restrict__ deg,
                                  const int* __restrict__ bsum,
                                  int* __restrict__ row_start,
                                  int* __restrict__ cursor) {
  __shared__ int sm[256];
  int t = threadIdx.x;
  int base = blockIdx.x * SCAN_CHUNK + t * 4;
  int4 d = {0, 0, 0, 0};
  if (t < 250) d = *reinterpret_cast<const int4*>(deg + base);
  int tot = d.x + d.y + d.z + d.w;
  sm[t] = tot;
  __syncthreads();
  for (int off = 1; off < 256; off <<= 1) {
    int u = 0;
    if (t >= off) u = sm[t - off];
    __syncthreads();
    if (t >= off) sm[t] += u;
    __syncthreads();
  }
  if (t < 250) {
    int run = bsum[blockIdx.x] + sm[t] - tot;
    int4 rs;
    rs.x = run;
    rs.y = run + d.x;
    rs.z = run + d.x + d.y;
    rs.w = run + d.x + d.y + d.z;
    *reinterpret_cast<int4*>(row_start + base) = rs;
    *reinterpret_cast<int4*>(cursor + base) = rs;
  }
}

// ---------------- fill CSR ----------------
__global__ void fill_csr_kernel(const int* __restrict__ src,
                                const int* __restrict__ dst,
                                int* __restrict__ cursor,
                                int* __restrict__ csr) {
  int e = blockIdx.x * blockDim.x + threadIdx.x;
  if (e >= NE) return;
  int pos = atomicAdd(&cursor[dst[e]], 1);
  csr[pos] = src[e];
}

// ---------------- hp = relu(x @ Wp + bp) fused with x->bf16; writes combined xh row ----------------
__global__ __launch_bounds__(512) void hp_gemm_kernel(const float* __restrict__ x,
                                                      const u16* __restrict__ wt,
                                                      const float* __restrict__ bp,
                                                      u16* __restrict__ xh) {
  __shared__ bf16x8 wl[1152];   // Wp^T
  int t = threadIdx.x;
  const bf16x8* wg = reinterpret_cast<const bf16x8*>(wt + 4 * 9216);
  for (int j = t; j < 1152; j += 512) wl[j] = wg[j];
  __syncthreads();
  int w = t >> 6, lane = t & 63;
  int i = lane & 15, g = lane >> 4;
  int row_base = blockIdx.x * 128 + w * 16;
  int grow_a = row_base + i;
  int lrow = grow_a < NN ? grow_a : NN - 1;
  const float4* xr = reinterpret_cast<const float4*>(x + (size_t)lrow * 96);
  bf16x8* xhv = reinterpret_cast<bf16x8*>(xh);
  bf16x8 ax[3];
#pragma unroll
  for (int kb = 0; kb < 3; ++kb) {
    float4 p = xr[(kb * 4 + g) * 2];
    float4 q = xr[(kb * 4 + g) * 2 + 1];
    bf16x8 v;
    v[0] = (short)f2b(p.x); v[1] = (short)f2b(p.y); v[2] = (short)f2b(p.z); v[3] = (short)f2b(p.w);
    v[4] = (short)f2b(q.x); v[5] = (short)f2b(q.y); v[6] = (short)f2b(q.z); v[7] = (short)f2b(q.w);
    ax[kb] = v;
    xhv[(size_t)grow_a * 24 + kb * 4 + g] = v;   // x half of combined row
  }
  for (int nt = 0; nt < 6; ++nt) {
    f32x4 acc = {0.f, 0.f, 0.f, 0.f};
    int bch = (nt * 16 + i) * 12;
#pragma unroll
    for (int kb = 0; kb < 3; ++kb)
      acc = MFMA16(ax[kb], wl[bch + kb * 4 + g], acc, 0, 0, 0);
    int col = nt * 16 + i;
    float bias = bp[col];
#pragma unroll
    for (int r = 0; r < 4; ++r) {
      int grow = row_base + g * 4 + r;
      xh[(size_t)grow * 192 + 96 + col] = f2b(fmaxf(acc[r] + bias, 0.0f));  // hp half
    }
  }
}

// ---------------- fused gather on combined rows ----------------
// 32 nodes/block, 8 slots/node; slot = t>>5 (wave-uniform role), node = t&31.
// slots 0-3: x-sum over chunks slot*3..+2 ; slots 4-7: hp-max over chunks slot*3..+2.
__global__ __launch_bounds__(256) void gather_kernel(const u16* __restrict__ xh,
                                                     const int* __restrict__ row_start,
                                                     const int* __restrict__ csr,
                                                     u16* __restrict__ hmbf,
                                                     u16* __restrict__ hxbf) {
  int t = threadIdx.x;
  int node = blockIdx.x * 32 + (t & 31);
  int slot = t >> 5;
  bool isMax = slot >= 4;
  if (node >= NN) return;
  int beg = row_start[node], end = row_start[node + 1];
  int cbase = slot * 3;
  const bf16x8* XH = reinterpret_cast<const bf16x8*>(xh);
  float acc0[8], acc1[8], acc2[8];
#pragma unroll
  for (int j = 0; j < 8; ++j) { acc0[j] = 0.f; acc1[j] = 0.f; acc2[j] = 0.f; }
  int e = beg;
  for (; e + 2 <= end; e += 2) {
    size_t b0 = (size_t)csr[e] * 24 + cbase;
    size_t b1 = (size_t)csr[e + 1] * 24 + cbase;
    bf16x8 a0 = XH[b0], a1 = XH[b0 + 1], a2 = XH[b0 + 2];
    bf16x8 c0 = XH[b1], c1 = XH[b1 + 1], c2 = XH[b1 + 2];
    if (isMax) {
#pragma unroll
      for (int j = 0; j < 8; ++j) {
        acc0[j] = fmaxf(acc0[j], fmaxf(b2f(a0[j]), b2f(c0[j])));
        acc1[j] = fmaxf(acc1[j], fmaxf(b2f(a1[j]), b2f(c1[j])));
        acc2[j] = fmaxf(acc2[j], fmaxf(b2f(a2[j]), b2f(c2[j])));
      }
    } else {
#pragma unroll
      for (int j = 0; j < 8; ++j) {
        acc0[j] += b2f(a0[j]) + b2f(c0[j]);
        acc1[j] += b2f(a1[j]) + b2f(c1[j]);
        acc2[j] += b2f(a2[j]) + b2f(c2[j]);
      }
    }
  }
  if (e < end) {
    size_t b0 = (size_t)csr[e] * 24 + cbase;
    bf16x8 a0 = XH[b0], a1 = XH[b0 + 1], a2 = XH[b0 + 2];
    if (isMax) {
#pragma unroll
      for (int j = 0; j < 8; ++j) {
        acc0[j] = fmaxf(acc0[j], b2f(a0[j]));
        acc1[j] = fmaxf(acc1[j], b2f(a1[j]));
        acc2[j] = fmaxf(acc2[j], b2f(a2[j]));
      }
    } else {
#pragma unroll
      for (int j = 0; j < 8; ++j) {
        acc0[j] += b2f(a0[j]);
        acc1[j] += b2f(a1[j]);
        acc2[j] += b2f(a2[j]);
      }
    }
  }
  float scl = isMax ? 1.0f : ((end > beg) ? 1.0f / (float)(end - beg) : 0.0f);
  bf16x8 v0, v1, v2;
#pragma unroll
  for (int j = 0; j < 8; ++j) {
    v0[j] = (short)f2b(acc0[j] * scl);
    v1[j] = (short)f2b(acc1[j] * scl);
    v2[j] = (short)f2b(acc2[j] * scl);
  }
  u16* dstp = isMax ? hxbf : hmbf;
  int ccol = isMax ? (slot - 4) * 3 : slot * 3;
  size_t ob = (size_t)node * 12 + ccol;
  bf16x8* dv = reinterpret_cast<bf16x8*>(dstp);
  dv[ob] = v0; dv[ob + 1] = v1; dv[ob + 2] = v2;
}

// ---------------- dual GEMM, all 4 weights in LDS ----------------
__global__ __launch_bounds__(512) void dualgemm_kernel(const u16* __restrict__ xh,
                                                       const u16* __restrict__ hmbf,
                                                       const u16* __restrict__ hxbf,
                                                       const u16* __restrict__ wt,
                                                       float* __restrict__ stats,
                                                       const float* __restrict__ params,
                                                       float* __restrict__ out,
                                                       int mode) {
  __shared__ bf16x8 wl[4608];
  __shared__ float smst[384];
  int t = threadIdx.x;
  const bf16x8* wg = reinterpret_cast<const bf16x8*>(wt);
  for (int j = t; j < 4608; j += 512) wl[j] = wg[j];
  if (mode == 0)
    for (int j = t; j < 384; j += 512) smst[j] = 0.f;
  __syncthreads();
  int w = t >> 6, lane = t & 63;
  int i = lane & 15, g = lane >> 4;
  int row_base = blockIdx.x * 128 + w * 16;
  size_t arowx = (size_t)(row_base + i) * 24;
  size_t arowh = (size_t)(row_base + i) * 12;
  bf16x8 ax[3], am[3], ah[3];
#pragma unroll
  for (int kb = 0; kb < 3; ++kb) {
    ax[kb] = reinterpret_cast<const bf16x8*>(xh)[arowx + kb * 4 + g];
    am[kb] = reinterpret_cast<const bf16x8*>(hmbf)[arowh + kb * 4 + g];
    ah[kb] = reinterpret_cast<const bf16x8*>(hxbf)[arowh + kb * 4 + g];
  }
  for (int nt = 0; nt < 6; ++nt) {
    f32x4 a1 = {0.f, 0.f, 0.f, 0.f}, a2 = {0.f, 0.f, 0.f, 0.f};
    int bch = (nt * 16 + i) * 12;
#pragma unroll
    for (int kb = 0; kb < 3; ++kb) {
      int bc = bch + kb * 4 + g;
      a1 = MFMA16(ax[kb], wl[bc], a1, 0, 0, 0);
      a1 = MFMA16(am[kb], wl[1152 + bc], a1, 0, 0, 0);
      a2 = MFMA16(ax[kb], wl[2304 + bc], a2, 0, 0, 0);
      a2 = MFMA16(ah[kb], wl[3456 + bc], a2, 0, 0, 0);
    }
    int col = nt * 16 + i;
    if (mode == 0) {
      float s1 = 0, q1 = 0, s2 = 0, q2 = 0;
#pragma unroll
      for (int r = 0; r < 4; ++r) {
        int grow = row_base + g * 4 + r;
        if (grow < NN) {
          float v = a1[r], u = a2[r];
          s1 += v; q1 += v * v; s2 += u; q2 += u * u;
        }
      }
      s1 += __shfl_xor(s1, 16); q1 += __shfl_xor(q1, 16);
      s2 += __shfl_xor(s2, 16); q2 += __shfl_xor(q2, 16);
      s1 += __shfl_xor(s1, 32); q1 += __shfl_xor(q1, 32);
      s2 += __shfl_xor(s2, 32); q2 += __shfl_xor(q2, 32);
      if (g == 0) {
        atomicAdd(&smst[col], s1);
        atomicAdd(&smst[96 + col], q1);
        atomicAdd(&smst[192 + col], s2);
        atomicAdd(&smst[288 + col], q2);
      }
    } else {
      float p1 = params[col], c1 = params[96 + col];
      float p2 = params[192 + col], c2 = params[288 + col];
#pragma unroll
      for (int r = 0; r < 4; ++r) {
        int grow = row_base + g * 4 + r;
        if (grow < NN) {
          float v = p1 * a1[r] + c1 + p2 * a2[r] + c2;
          v = v > 0.f ? v : 0.01f * v;
          out[(size_t)grow * 96 + col] = v;
        }
      }
    }
  }
  if (mode == 0) {
    __syncthreads();
    for (int j = t; j < 384; j += 512) atomicAdd(&stats[j], smst[j]);
  }
}

// ---------------- fold BN into per-column affine ----------------
__global__ void finalize_kernel(const float* __restrict__ stats,
                                const float* __restrict__ g1, const float* __restrict__ beta1,
                                const float* __restrict__ g2, const float* __restrict__ beta2,
                                float* __restrict__ params) {
  int c = threadIdx.x;
  if (c >= 96) return;
  const float inv_n = 1.0f / NN;
  float mu1 = stats[c] * inv_n;
  float var1 = fmaxf(stats[96 + c] * inv_n - mu1 * mu1, 0.0f);
  float is1 = rsqrtf(var1 + 1e-5f);
  float a1 = g1[c] * is1;
  params[c] = a1;
  params[96 + c] = beta1[c] - a1 * mu1;
  float mu2 = stats[192 + c] * inv_n;
  float var2 = fmaxf(stats[288 + c] * inv_n - mu2 * mu2, 0.0f);
  float is2 = rsqrtf(var2 + 1e-5f);
  float a2 = g2[c] * is2;
  params[192 + c] = a2;
  params[288 + c] = beta2[c] - a2 * mu2;
}

extern "C" void kernel_launch(void* const* d_in, const int* in_sizes, int n_in,
                              void* d_out, int out_size, void* d_ws, size_t ws_size,
                              hipStream_t stream) {
  const float* x       = (const float*)d_in[0];
  const int*   ei      = (const int*)d_in[1];
  const float* W_self1 = (const float*)d_in[2];
  const float* W_neigh1= (const float*)d_in[3];
  const float* W_pool  = (const float*)d_in[4];
  const float* b_pool  = (const float*)d_in[5];
  const float* W_self2 = (const float*)d_in[6];
  const float* W_neigh2= (const float*)d_in[7];
  const float* g1      = (const float*)d_in[8];
  const float* beta1   = (const float*)d_in[9];
  const float* g2      = (const float*)d_in[10];
  const float* beta2   = (const float*)d_in[11];
  float* out = (float*)d_out;

  float* ws = (float*)d_ws;
  int*   deg       = (int*)(ws + OFF_DEG);
  int*   row_start = (int*)(ws + OFF_ROWSTART);
  int*   cursor    = (int*)(ws + OFF_CURSOR);
  int*   bsum      = (int*)(ws + OFF_BSUM);
  float* stats     = ws + OFF_STATS;
  float* params    = ws + OFF_PARAMS;
  u16*   wt        = (u16*)(ws + OFF_WT);
  int*   csr       = (int*)(ws + OFF_CSR);
  u16*   xh        = (u16*)(ws + OFF_XH);
  u16*   hmbf      = (u16*)(ws + OFF_HMBF);
  u16*   hxbf      = (u16*)(ws + OFF_HXBF);

  const int* src = ei;
  const int* dst = ei + NE;

  hipMemsetAsync(deg, 0, NN * sizeof(int), stream);
  hipMemsetAsync(stats, 0, 384 * sizeof(float), stream);

  wprep_kernel<<<(5 * 9216 + 255) / 256, 256, 0, stream>>>(W_self1, W_neigh1, W_self2,
                                                           W_neigh2, W_pool, wt);

  deg_kernel<<<(NE + 255) / 256, 256, 0, stream>>>(dst, deg);
  scan_sum_kernel<<<SCAN_BLOCKS, 256, 0, stream>>>(deg, bsum);
  scan_bsum_kernel<<<1, 128, 0, stream>>>(bsum, row_start);
  scan_final_kernel<<<SCAN_BLOCKS, 256, 0, stream>>>(deg, bsum, row_start, cursor);
  fill_csr_kernel<<<(NE + 255) / 256, 256, 0, stream>>>(src, dst, cursor, csr);

  // hp = relu(x @ Wp + bp) fused with x->bf16 conversion into combined rows
  hp_gemm_kernel<<<GBLK, 512, 0, stream>>>(x, wt, b_pool, xh);

  gather_kernel<<<(NN + 31) / 32, 256, 0, stream>>>(xh, row_start, csr, hmbf, hxbf);

  dualgemm_kernel<<<GBLK, 512, 0, stream>>>(xh, hmbf, hxbf, wt, stats, params, out, 0);
  finalize_kernel<<<1, 128, 0, stream>>>(stats, g1, beta1, g2, beta2, params);
  dualgemm_kernel<<<GBLK, 512, 0, stream>>>(xh, hmbf, hxbf, wt, stats, params, out, 1);
}

// Round 7
// 274.183 us; speedup vs baseline: 8.0086x; 1.0140x over previous
//
#include <hip/hip_runtime.h>

#define NN 100000
#define NE 800000
#define DD 96
#define NROWPAD 100096            // 391 * 256
#define GBLK 782                  // hp blocks (128 rows each)
#define DBLK 391                  // dualgemm blocks (256 rows each)
#define SCAN_BLOCKS 100
#define SCAN_CHUNK 1000

typedef __attribute__((ext_vector_type(8))) short bf16x8;
typedef __attribute__((ext_vector_type(4))) float f32x4;
typedef unsigned short u16;
typedef unsigned int u32;

#define MFMA16 __builtin_amdgcn_mfma_f32_16x16x32_bf16

// workspace layout (4-byte element offsets)
#define OFF_DEG      0u          // NN ints
#define OFF_ROWSTART 100000u     // NN+1 ints
#define OFF_CURSOR   200004u     // NN ints
#define OFF_BSUM     300004u     // 128 ints
#define OFF_STATS    300132u     // 384 floats
#define OFF_PARAMS   300516u     // 384 floats
#define OFF_WT       300900u     // 5*9216 bf16
#define OFF_CSR      323940u     // NE ints
#define OFF_XH       1123940u    // NROWPAD*96 floats (combined x|hp bf16 rows, 384B)
#define OFF_HMBF     10733156u   // NROWPAD*48 floats (bf16 rows) -> becomes o1
#define OFF_HXBF     15537764u   // NROWPAD*48 floats            -> becomes o2

__device__ __forceinline__ u16 f2b(float f) {
  u32 u = __float_as_uint(f);
  u += 0x7FFFu + ((u >> 16) & 1u);
  return (u16)(u >> 16);
}
__device__ __forceinline__ float b2f(short h) {
  return __uint_as_float(((u32)(u16)h) << 16);
}

// ---------------- weight prep ----------------
__global__ void wprep_kernel(const float* __restrict__ Ws1, const float* __restrict__ Wn1,
                             const float* __restrict__ Ws2, const float* __restrict__ Wn2,
                             const float* __restrict__ Wp, u16* __restrict__ wt) {
  int idx = blockIdx.x * 256 + threadIdx.x;
  if (idx >= 5 * 9216) return;
  int m = idx / 9216, r = idx % 9216;
  int k = r / 96, c = r % 96;
  const float* W = (m == 0) ? Ws1 : (m == 1) ? Wn1 : (m == 2) ? Ws2 : (m == 3) ? Wn2 : Wp;
  wt[m * 9216 + c * 96 + k] = f2b(W[k * 96 + c]);
}

// ---------------- degree histogram ----------------
__global__ void deg_kernel(const int* __restrict__ dst, int* __restrict__ deg) {
  int e = blockIdx.x * blockDim.x + threadIdx.x;
  if (e >= NE) return;
  atomicAdd(&deg[dst[e]], 1);
}

// ---------------- scan phase 1 ----------------
__global__ void scan_sum_kernel(const int* __restrict__ deg, int* __restrict__ bsum) {
  __shared__ int red[256];
  int t = threadIdx.x;
  int base = blockIdx.x * SCAN_CHUNK;
  int s = 0;
  for (int i = t; i < SCAN_CHUNK; i += 256) s += deg[base + i];
  red[t] = s;
  __syncthreads();
  for (int off = 128; off > 0; off >>= 1) {
    if (t < off) red[t] += red[t + off];
    __syncthreads();
  }
  if (t == 0) bsum[blockIdx.x] = red[0];
}

// ---------------- scan phase 2 ----------------
__global__ void scan_bsum_kernel(int* __restrict__ bsum, int* __restrict__ row_start) {
  __shared__ int sm[128];
  int t = threadIdx.x;
  int v = (t < SCAN_BLOCKS) ? bsum[t] : 0;
  sm[t] = v;
  __syncthreads();
  for (int off = 1; off < 128; off <<= 1) {
    int u = 0;
    if (t >= off) u = sm[t - off];
    __syncthreads();
    if (t >= off) sm[t] += u;
    __syncthreads();
  }
  if (t < SCAN_BLOCKS) bsum[t] = sm[t] - v;
  if (t == SCAN_BLOCKS - 1) row_start[NN] = sm[t];
}

// ---------------- scan phase 3 ----------------
__global__ void scan_final_kernel(const int* __restrict__ deg,
                                  const int* __restrict__ bsum,
                                  int* __restrict__ row_start,
                                  int* __restrict__ cursor) {
  __shared__ int sm[256];
  int t = threadIdx.x;
  int base = blockIdx.x * SCAN_CHUNK + t * 4;
  int4 d = {0, 0, 0, 0};
  if (t < 250) d = *reinterpret_cast<const int4*>(deg + base);
  int tot = d.x + d.y + d.z + d.w;
  sm[t] = tot;
  __syncthreads();
  for (int off = 1; off < 256; off <<= 1) {
    int u = 0;
    if (t >= off) u = sm[t - off];
    __syncthreads();
    if (t >= off) sm[t] += u;
    __syncthreads();
  }
  if (t < 250) {
    int run = bsum[blockIdx.x] + sm[t] - tot;
    int4 rs;
    rs.x = run;
    rs.y = run + d.x;
    rs.z = run + d.x + d.y;
    rs.w = run + d.x + d.y + d.z;
    *reinterpret_cast<int4*>(row_start + base) = rs;
    *reinterpret_cast<int4*>(cursor + base) = rs;
  }
}

// ---------------- fill CSR ----------------
__global__ void fill_csr_kernel(const int* __restrict__ src,
                                const int* __restrict__ dst,
                                int* __restrict__ cursor,
                                int* __restrict__ csr) {
  int e = blockIdx.x * blockDim.x + threadIdx.x;
  if (e >= NE) return;
  int pos = atomicAdd(&cursor[dst[e]], 1);
  csr[pos] = src[e];
}

// ---------------- hp = relu(x @ Wp + bp) fused with x->bf16; combined xh row ----------------
__global__ __launch_bounds__(512) void hp_gemm_kernel(const float* __restrict__ x,
                                                      const u16* __restrict__ wt,
                                                      const float* __restrict__ bp,
                                                      u16* __restrict__ xh) {
  __shared__ bf16x8 wl[1152];   // Wp^T
  int t = threadIdx.x;
  const bf16x8* wg = reinterpret_cast<const bf16x8*>(wt + 4 * 9216);
  for (int j = t; j < 1152; j += 512) wl[j] = wg[j];
  __syncthreads();
  int w = t >> 6, lane = t & 63;
  int i = lane & 15, g = lane >> 4;
  int row_base = blockIdx.x * 128 + w * 16;
  int grow_a = row_base + i;
  int lrow = grow_a < NN ? grow_a : NN - 1;
  const float4* xr = reinterpret_cast<const float4*>(x + (size_t)lrow * 96);
  bf16x8* xhv = reinterpret_cast<bf16x8*>(xh);
  bf16x8 ax[3];
#pragma unroll
  for (int kb = 0; kb < 3; ++kb) {
    float4 p = xr[(kb * 4 + g) * 2];
    float4 q = xr[(kb * 4 + g) * 2 + 1];
    bf16x8 v;
    v[0] = (short)f2b(p.x); v[1] = (short)f2b(p.y); v[2] = (short)f2b(p.z); v[3] = (short)f2b(p.w);
    v[4] = (short)f2b(q.x); v[5] = (short)f2b(q.y); v[6] = (short)f2b(q.z); v[7] = (short)f2b(q.w);
    ax[kb] = v;
    xhv[(size_t)grow_a * 24 + kb * 4 + g] = v;
  }
  for (int nt = 0; nt < 6; ++nt) {
    f32x4 acc = {0.f, 0.f, 0.f, 0.f};
    int bch = (nt * 16 + i) * 12;
#pragma unroll
    for (int kb = 0; kb < 3; ++kb)
      acc = MFMA16(ax[kb], wl[bch + kb * 4 + g], acc, 0, 0, 0);
    int col = nt * 16 + i;
    float bias = bp[col];
#pragma unroll
    for (int r = 0; r < 4; ++r) {
      int grow = row_base + g * 4 + r;
      xh[(size_t)grow * 192 + 96 + col] = f2b(fmaxf(acc[r] + bias, 0.0f));
    }
  }
}

// ---------------- fused gather: 32 nodes/block, 12 slots/node, 2 chunks/slot ----------------
// slots 0-5: x-sum over chunks 2s,2s+1 ; slots 6-11: hp-max over chunks 2s,2s+1 (=12..23).
__global__ __launch_bounds__(384) void gather_kernel(const u16* __restrict__ xh,
                                                     const int* __restrict__ row_start,
                                                     const int* __restrict__ csr,
                                                     u16* __restrict__ hmbf,
                                                     u16* __restrict__ hxbf) {
  int t = threadIdx.x;
  int node = blockIdx.x * 32 + (t & 31);
  int slot = t >> 5;            // 0..11, wave-uniform in pairs
  bool isMax = slot >= 6;
  if (node >= NN) return;
  int beg = row_start[node], end = row_start[node + 1];
  int cbase = slot * 2;         // chunk index into 24-chunk combined row
  const bf16x8* XH = reinterpret_cast<const bf16x8*>(xh);
  float a0[8], a1[8];
#pragma unroll
  for (int j = 0; j < 8; ++j) { a0[j] = 0.f; a1[j] = 0.f; }
  int e = beg;
  for (; e + 4 <= end; e += 4) {
    size_t b0 = (size_t)csr[e] * 24 + cbase;
    size_t b1 = (size_t)csr[e + 1] * 24 + cbase;
    size_t b2 = (size_t)csr[e + 2] * 24 + cbase;
    size_t b3 = (size_t)csr[e + 3] * 24 + cbase;
    bf16x8 u0 = XH[b0], v0 = XH[b0 + 1];
    bf16x8 u1 = XH[b1], v1 = XH[b1 + 1];
    bf16x8 u2 = XH[b2], v2 = XH[b2 + 1];
    bf16x8 u3 = XH[b3], v3 = XH[b3 + 1];
    if (isMax) {
#pragma unroll
      for (int j = 0; j < 8; ++j) {
        a0[j] = fmaxf(a0[j], fmaxf(fmaxf(b2f(u0[j]), b2f(u1[j])), fmaxf(b2f(u2[j]), b2f(u3[j]))));
        a1[j] = fmaxf(a1[j], fmaxf(fmaxf(b2f(v0[j]), b2f(v1[j])), fmaxf(b2f(v2[j]), b2f(v3[j]))));
      }
    } else {
#pragma unroll
      for (int j = 0; j < 8; ++j) {
        a0[j] += (b2f(u0[j]) + b2f(u1[j])) + (b2f(u2[j]) + b2f(u3[j]));
        a1[j] += (b2f(v0[j]) + b2f(v1[j])) + (b2f(v2[j]) + b2f(v3[j]));
      }
    }
  }
  for (; e < end; ++e) {
    size_t b0 = (size_t)csr[e] * 24 + cbase;
    bf16x8 u0 = XH[b0], v0 = XH[b0 + 1];
    if (isMax) {
#pragma unroll
      for (int j = 0; j < 8; ++j) {
        a0[j] = fmaxf(a0[j], b2f(u0[j]));
        a1[j] = fmaxf(a1[j], b2f(v0[j]));
      }
    } else {
#pragma unroll
      for (int j = 0; j < 8; ++j) {
        a0[j] += b2f(u0[j]);
        a1[j] += b2f(v0[j]);
      }
    }
  }
  float scl = isMax ? 1.0f : ((end > beg) ? 1.0f / (float)(end - beg) : 0.0f);
  bf16x8 w0, w1;
#pragma unroll
  for (int j = 0; j < 8; ++j) {
    w0[j] = (short)f2b(a0[j] * scl);
    w1[j] = (short)f2b(a1[j] * scl);
  }
  u16* dstp = isMax ? hxbf : hmbf;
  int outc = isMax ? (slot - 6) * 2 : slot * 2;
  bf16x8* dv = reinterpret_cast<bf16x8*>(dstp);
  size_t ob = (size_t)node * 12 + outc;
  dv[ob] = w0; dv[ob + 1] = w1;
}

// ---------------- single-pass dual GEMM: stats + store o1/o2 bf16 in place ----------------
__global__ __launch_bounds__(1024) void dualgemm_kernel(const u16* __restrict__ xh,
                                                        u16* __restrict__ hmbf,
                                                        u16* __restrict__ hxbf,
                                                        const u16* __restrict__ wt,
                                                        float* __restrict__ stats) {
  __shared__ bf16x8 wl[4608];
  __shared__ float smst[384];
  int t = threadIdx.x;
  const bf16x8* wg = reinterpret_cast<const bf16x8*>(wt);
  for (int j = t; j < 4608; j += 1024) wl[j] = wg[j];
  for (int j = t; j < 384; j += 1024) smst[j] = 0.f;
  __syncthreads();
  int w = t >> 6, lane = t & 63;
  int i = lane & 15, g = lane >> 4;
  int row_base = blockIdx.x * 256 + w * 16;
  size_t arowx = (size_t)(row_base + i) * 24;
  size_t arowh = (size_t)(row_base + i) * 12;
  bf16x8 ax[3], am[3], ah[3];
#pragma unroll
  for (int kb = 0; kb < 3; ++kb) {
    ax[kb] = reinterpret_cast<const bf16x8*>(xh)[arowx + kb * 4 + g];
    am[kb] = reinterpret_cast<const bf16x8*>(hmbf)[arowh + kb * 4 + g];
    ah[kb] = reinterpret_cast<const bf16x8*>(hxbf)[arowh + kb * 4 + g];
  }
  __syncthreads();   // all reads of hm/hx done before in-place overwrite below
  for (int nt = 0; nt < 6; ++nt) {
    f32x4 a1 = {0.f, 0.f, 0.f, 0.f}, a2 = {0.f, 0.f, 0.f, 0.f};
    int bch = (nt * 16 + i) * 12;
#pragma unroll
    for (int kb = 0; kb < 3; ++kb) {
      int bc = bch + kb * 4 + g;
      a1 = MFMA16(ax[kb], wl[bc], a1, 0, 0, 0);
      a1 = MFMA16(am[kb], wl[1152 + bc], a1, 0, 0, 0);
      a2 = MFMA16(ax[kb], wl[2304 + bc], a2, 0, 0, 0);
      a2 = MFMA16(ah[kb], wl[3456 + bc], a2, 0, 0, 0);
    }
    int col = nt * 16 + i;
    float s1 = 0, q1 = 0, s2 = 0, q2 = 0;
#pragma unroll
    for (int r = 0; r < 4; ++r) {
      int grow = row_base + g * 4 + r;
      if (grow < NN) {
        float v = a1[r], u = a2[r];
        s1 += v; q1 += v * v; s2 += u; q2 += u * u;
        hmbf[(size_t)grow * 96 + col] = f2b(v);
        hxbf[(size_t)grow * 96 + col] = f2b(u);
      }
    }
    s1 += __shfl_xor(s1, 16); q1 += __shfl_xor(q1, 16);
    s2 += __shfl_xor(s2, 16); q2 += __shfl_xor(q2, 16);
    s1 += __shfl_xor(s1, 32); q1 += __shfl_xor(q1, 32);
    s2 += __shfl_xor(s2, 32); q2 += __shfl_xor(q2, 32);
    if (g == 0) {
      atomicAdd(&smst[col], s1);
      atomicAdd(&smst[96 + col], q1);
      atomicAdd(&smst[192 + col], s2);
      atomicAdd(&smst[288 + col], q2);
    }
  }
  __syncthreads();
  for (int j = t; j < 384; j += 1024) atomicAdd(&stats[j], smst[j]);
}

// ---------------- fold BN into per-column affine ----------------
__global__ void finalize_kernel(const float* __restrict__ stats,
                                const float* __restrict__ g1, const float* __restrict__ beta1,
                                const float* __restrict__ g2, const float* __restrict__ beta2,
                                float* __restrict__ params) {
  int c = threadIdx.x;
  if (c >= 96) return;
  const float inv_n = 1.0f / NN;
  float mu1 = stats[c] * inv_n;
  float var1 = fmaxf(stats[96 + c] * inv_n - mu1 * mu1, 0.0f);
  float is1 = rsqrtf(var1 + 1e-5f);
  float a1 = g1[c] * is1;
  params[c] = a1;
  params[96 + c] = beta1[c] - a1 * mu1;
  float mu2 = stats[192 + c] * inv_n;
  float var2 = fmaxf(stats[288 + c] * inv_n - mu2 * mu2, 0.0f);
  float is2 = rsqrtf(var2 + 1e-5f);
  float a2 = g2[c] * is2;
  params[192 + c] = a2;
  params[288 + c] = beta2[c] - a2 * mu2;
}

// ---------------- out = leaky(bn1(o1)+bn2(o2)), streaming ----------------
__global__ __launch_bounds__(256) void final_kernel(const u16* __restrict__ o1,
                                                    const u16* __restrict__ o2,
                                                    const float* __restrict__ params,
                                                    float* __restrict__ out) {
  int idx = blockIdx.x * 256 + threadIdx.x;   // one bf16x8 chunk
  if (idx >= NN * 12) return;
  int c8 = idx % 12;
  bf16x8 v1 = reinterpret_cast<const bf16x8*>(o1)[idx];
  bf16x8 v2 = reinterpret_cast<const bf16x8*>(o2)[idx];
  const float4* P = reinterpret_cast<const float4*>(params);
  float4 A1l = P[c8 * 2],      A1h = P[c8 * 2 + 1];
  float4 B1l = P[24 + c8 * 2], B1h = P[24 + c8 * 2 + 1];
  float4 A2l = P[48 + c8 * 2], A2h = P[48 + c8 * 2 + 1];
  float4 B2l = P[72 + c8 * 2], B2h = P[72 + c8 * 2 + 1];
  float A1[8] = {A1l.x, A1l.y, A1l.z, A1l.w, A1h.x, A1h.y, A1h.z, A1h.w};
  float B1[8] = {B1l.x, B1l.y, B1l.z, B1l.w, B1h.x, B1h.y, B1h.z, B1h.w};
  float A2[8] = {A2l.x, A2l.y, A2l.z, A2l.w, A2h.x, A2h.y, A2h.z, A2h.w};
  float B2[8] = {B2l.x, B2l.y, B2l.z, B2l.w, B2h.x, B2h.y, B2h.z, B2h.w};
  float o[8];
#pragma unroll
  for (int j = 0; j < 8; ++j) {
    float v = A1[j] * b2f(v1[j]) + B1[j] + A2[j] * b2f(v2[j]) + B2[j];
    o[j] = v > 0.f ? v : 0.01f * v;
  }
  float4* ov = reinterpret_cast<float4*>(out);
  float4 lo = {o[0], o[1], o[2], o[3]}, hi = {o[4], o[5], o[6], o[7]};
  ov[idx * 2] = lo;
  ov[idx * 2 + 1] = hi;
}

extern "C" void kernel_launch(void* const* d_in, const int* in_sizes, int n_in,
                              void* d_out, int out_size, void* d_ws, size_t ws_size,
                              hipStream_t stream) {
  const float* x       = (const float*)d_in[0];
  const int*   ei      = (const int*)d_in[1];
  const float* W_self1 = (const float*)d_in[2];
  const float* W_neigh1= (const float*)d_in[3];
  const float* W_pool  = (const float*)d_in[4];
  const float* b_pool  = (const float*)d_in[5];
  const float* W_self2 = (const float*)d_in[6];
  const float* W_neigh2= (const float*)d_in[7];
  const float* g1      = (const float*)d_in[8];
  const float* beta1   = (const float*)d_in[9];
  const float* g2      = (const float*)d_in[10];
  const float* beta2   = (const float*)d_in[11];
  float* out = (float*)d_out;

  float* ws = (float*)d_ws;
  int*   deg       = (int*)(ws + OFF_DEG);
  int*   row_start = (int*)(ws + OFF_ROWSTART);
  int*   cursor    = (int*)(ws + OFF_CURSOR);
  int*   bsum      = (int*)(ws + OFF_BSUM);
  float* stats     = ws + OFF_STATS;
  float* params    = ws + OFF_PARAMS;
  u16*   wt        = (u16*)(ws + OFF_WT);
  int*   csr       = (int*)(ws + OFF_CSR);
  u16*   xh        = (u16*)(ws + OFF_XH);
  u16*   hmbf      = (u16*)(ws + OFF_HMBF);
  u16*   hxbf      = (u16*)(ws + OFF_HXBF);

  const int* src = ei;
  const int* dst = ei + NE;

  hipMemsetAsync(deg, 0, NN * sizeof(int), stream);
  hipMemsetAsync(stats, 0, 384 * sizeof(float), stream);

  wprep_kernel<<<(5 * 9216 + 255) / 256, 256, 0, stream>>>(W_self1, W_neigh1, W_self2,
                                                           W_neigh2, W_pool, wt);

  deg_kernel<<<(NE + 255) / 256, 256, 0, stream>>>(dst, deg);
  scan_sum_kernel<<<SCAN_BLOCKS, 256, 0, stream>>>(deg, bsum);
  scan_bsum_kernel<<<1, 128, 0, stream>>>(bsum, row_start);
  scan_final_kernel<<<SCAN_BLOCKS, 256, 0, stream>>>(deg, bsum, row_start, cursor);
  fill_csr_kernel<<<(NE + 255) / 256, 256, 0, stream>>>(src, dst, cursor, csr);

  hp_gemm_kernel<<<GBLK, 512, 0, stream>>>(x, wt, b_pool, xh);

  gather_kernel<<<(NN + 31) / 32, 384, 0, stream>>>(xh, row_start, csr, hmbf, hxbf);

  dualgemm_kernel<<<DBLK, 1024, 0, stream>>>(xh, hmbf, hxbf, wt, stats);
  finalize_kernel<<<1, 128, 0, stream>>>(stats, g1, beta1, g2, beta2, params);
  final_kernel<<<(NN * 12 + 255) / 256, 256, 0, stream>>>(hmbf, hxbf, params, out);
}

// Round 8
// 260.991 us; speedup vs baseline: 8.4134x; 1.0505x over previous
//
#include <hip/hip_runtime.h>

#define NN 100000
#define NE 800000
#define DD 96
#define NROWPAD 100096            // 391 * 256
#define GBLK 782                  // hp blocks (128 rows each)
#define DBLK 391                  // dualgemm blocks (256 rows each)
#define SCAN_BLOCKS 100
#define SCAN_CHUNK 1000

typedef __attribute__((ext_vector_type(8))) short bf16x8;
typedef __attribute__((ext_vector_type(8))) unsigned short u16x8;
typedef __attribute__((ext_vector_type(4))) float f32x4;
typedef unsigned short u16;
typedef unsigned int u32;

#define MFMA16 __builtin_amdgcn_mfma_f32_16x16x32_bf16

// workspace layout (4-byte element offsets)
#define OFF_DEG      0u          // NN ints
#define OFF_ROWSTART 100000u     // NN+1 ints
#define OFF_CURSOR   200004u     // NN ints
#define OFF_BSUM     300004u     // 128 ints
#define OFF_STATS    300132u     // 384 floats
#define OFF_PARAMS   300516u     // 384 floats
#define OFF_WT       300900u     // 5*9216 bf16
#define OFF_CSR      323940u     // NE ints
#define OFF_XH       1123940u    // NROWPAD*96 floats (combined x|hp bf16 rows, 384B)
#define OFF_HMBF     10733156u   // NROWPAD*48 floats (bf16 rows) -> becomes o1
#define OFF_HXBF     15537764u   // NROWPAD*48 floats            -> becomes o2

__device__ __forceinline__ u16 f2b(float f) {
  u32 u = __float_as_uint(f);
  u += 0x7FFFu + ((u >> 16) & 1u);
  return (u16)(u >> 16);
}
__device__ __forceinline__ float b2f(short h) {
  return __uint_as_float(((u32)(u16)h) << 16);
}

// ---------------- weight prep ----------------
__global__ void wprep_kernel(const float* __restrict__ Ws1, const float* __restrict__ Wn1,
                             const float* __restrict__ Ws2, const float* __restrict__ Wn2,
                             const float* __restrict__ Wp, u16* __restrict__ wt) {
  int idx = blockIdx.x * 256 + threadIdx.x;
  if (idx >= 5 * 9216) return;
  int m = idx / 9216, r = idx % 9216;
  int k = r / 96, c = r % 96;
  const float* W = (m == 0) ? Ws1 : (m == 1) ? Wn1 : (m == 2) ? Ws2 : (m == 3) ? Wn2 : Wp;
  wt[m * 9216 + c * 96 + k] = f2b(W[k * 96 + c]);
}

// ---------------- degree histogram ----------------
__global__ void deg_kernel(const int* __restrict__ dst, int* __restrict__ deg) {
  int e = blockIdx.x * blockDim.x + threadIdx.x;
  if (e >= NE) return;
  atomicAdd(&deg[dst[e]], 1);
}

// ---------------- scan phase 1 ----------------
__global__ void scan_sum_kernel(const int* __restrict__ deg, int* __restrict__ bsum) {
  __shared__ int red[256];
  int t = threadIdx.x;
  int base = blockIdx.x * SCAN_CHUNK;
  int s = 0;
  for (int i = t; i < SCAN_CHUNK; i += 256) s += deg[base + i];
  red[t] = s;
  __syncthreads();
  for (int off = 128; off > 0; off >>= 1) {
    if (t < off) red[t] += red[t + off];
    __syncthreads();
  }
  if (t == 0) bsum[blockIdx.x] = red[0];
}

// ---------------- scan phase 2 ----------------
__global__ void scan_bsum_kernel(int* __restrict__ bsum, int* __restrict__ row_start) {
  __shared__ int sm[128];
  int t = threadIdx.x;
  int v = (t < SCAN_BLOCKS) ? bsum[t] : 0;
  sm[t] = v;
  __syncthreads();
  for (int off = 1; off < 128; off <<= 1) {
    int u = 0;
    if (t >= off) u = sm[t - off];
    __syncthreads();
    if (t >= off) sm[t] += u;
    __syncthreads();
  }
  if (t < SCAN_BLOCKS) bsum[t] = sm[t] - v;
  if (t == SCAN_BLOCKS - 1) row_start[NN] = sm[t];
}

// ---------------- scan phase 3 ----------------
__global__ void scan_final_kernel(const int* __restrict__ deg,
                                  const int* __restrict__ bsum,
                                  int* __restrict__ row_start,
                                  int* __restrict__ cursor) {
  __shared__ int sm[256];
  int t = threadIdx.x;
  int base = blockIdx.x * SCAN_CHUNK + t * 4;
  int4 d = {0, 0, 0, 0};
  if (t < 250) d = *reinterpret_cast<const int4*>(deg + base);
  int tot = d.x + d.y + d.z + d.w;
  sm[t] = tot;
  __syncthreads();
  for (int off = 1; off < 256; off <<= 1) {
    int u = 0;
    if (t >= off) u = sm[t - off];
    __syncthreads();
    if (t >= off) sm[t] += u;
    __syncthreads();
  }
  if (t < 250) {
    int run = bsum[blockIdx.x] + sm[t] - tot;
    int4 rs;
    rs.x = run;
    rs.y = run + d.x;
    rs.z = run + d.x + d.y;
    rs.w = run + d.x + d.y + d.z;
    *reinterpret_cast<int4*>(row_start + base) = rs;
    *reinterpret_cast<int4*>(cursor + base) = rs;
  }
}

// ---------------- fill CSR ----------------
__global__ void fill_csr_kernel(const int* __restrict__ src,
                                const int* __restrict__ dst,
                                int* __restrict__ cursor,
                                int* __restrict__ csr) {
  int e = blockIdx.x * blockDim.x + threadIdx.x;
  if (e >= NE) return;
  int pos = atomicAdd(&cursor[dst[e]], 1);
  csr[pos] = src[e];
}

// ---------------- hp = relu(x @ Wp + bp) fused with x->bf16; combined xh row ----------------
__global__ __launch_bounds__(512) void hp_gemm_kernel(const float* __restrict__ x,
                                                      const u16* __restrict__ wt,
                                                      const float* __restrict__ bp,
                                                      u16* __restrict__ xh) {
  __shared__ bf16x8 wl[1152];   // Wp^T
  int t = threadIdx.x;
  const bf16x8* wg = reinterpret_cast<const bf16x8*>(wt + 4 * 9216);
  for (int j = t; j < 1152; j += 512) wl[j] = wg[j];
  __syncthreads();
  int w = t >> 6, lane = t & 63;
  int i = lane & 15, g = lane >> 4;
  int row_base = blockIdx.x * 128 + w * 16;
  int grow_a = row_base + i;
  int lrow = grow_a < NN ? grow_a : NN - 1;
  const float4* xr = reinterpret_cast<const float4*>(x + (size_t)lrow * 96);
  bf16x8* xhv = reinterpret_cast<bf16x8*>(xh);
  bf16x8 ax[3];
#pragma unroll
  for (int kb = 0; kb < 3; ++kb) {
    float4 p = xr[(kb * 4 + g) * 2];
    float4 q = xr[(kb * 4 + g) * 2 + 1];
    bf16x8 v;
    v[0] = (short)f2b(p.x); v[1] = (short)f2b(p.y); v[2] = (short)f2b(p.z); v[3] = (short)f2b(p.w);
    v[4] = (short)f2b(q.x); v[5] = (short)f2b(q.y); v[6] = (short)f2b(q.z); v[7] = (short)f2b(q.w);
    ax[kb] = v;
    xhv[(size_t)grow_a * 24 + kb * 4 + g] = v;
  }
  for (int nt = 0; nt < 6; ++nt) {
    f32x4 acc = {0.f, 0.f, 0.f, 0.f};
    int bch = (nt * 16 + i) * 12;
#pragma unroll
    for (int kb = 0; kb < 3; ++kb)
      acc = MFMA16(ax[kb], wl[bch + kb * 4 + g], acc, 0, 0, 0);
    int col = nt * 16 + i;
    float bias = bp[col];
#pragma unroll
    for (int r = 0; r < 4; ++r) {
      int grow = row_base + g * 4 + r;
      xh[(size_t)grow * 192 + 96 + col] = f2b(fmaxf(acc[r] + bias, 0.0f));
    }
  }
}

// ---------------- fused gather: 32 nodes/block, 8 slots/node, 3 chunks/slot ----------------
// slots 0-3: x-sum (fp32); slots 4-7: hp-max (u16 bit-compare, valid since hp>=0).
// csr index stream is software-pipelined to hide L2 latency under row loads.
__global__ __launch_bounds__(256) void gather_kernel(const u16* __restrict__ xh,
                                                     const int* __restrict__ row_start,
                                                     const int* __restrict__ csr,
                                                     u16* __restrict__ hmbf,
                                                     u16* __restrict__ hxbf) {
  int t = threadIdx.x;
  int node = blockIdx.x * 32 + (t & 31);
  int slot = t >> 5;            // 0..7; sum/max split at wave boundary
  bool isMax = slot >= 4;
  if (node >= NN) return;
  int beg = row_start[node], end = row_start[node + 1];
  int cbase = slot * 3;
  const u16x8* XH = reinterpret_cast<const u16x8*>(xh);
  float s0[8], s1[8], s2[8];
  u16x8 m0, m1, m2;
#pragma unroll
  for (int j = 0; j < 8; ++j) {
    s0[j] = 0.f; s1[j] = 0.f; s2[j] = 0.f;
    m0[j] = 0; m1[j] = 0; m2[j] = 0;
  }
  int e = beg;
  // prefetch first two indices (clamped, loads always in-bounds of workspace)
  int i0 = csr[(e < end) ? e : 0];
  int i1 = csr[(e + 1 < end) ? e + 1 : ((end > beg) ? end - 1 : 0)];
  for (; e + 2 <= end; e += 2) {
    int p2 = e + 2, p3 = e + 3;
    int n0 = csr[(p2 < end) ? p2 : end - 1];
    int n1 = csr[(p3 < end) ? p3 : end - 1];
    size_t b0 = (size_t)i0 * 24 + cbase;
    size_t b1 = (size_t)i1 * 24 + cbase;
    u16x8 u0 = XH[b0], u1 = XH[b0 + 1], u2 = XH[b0 + 2];
    u16x8 v0 = XH[b1], v1 = XH[b1 + 1], v2 = XH[b1 + 2];
    if (isMax) {
#pragma unroll
      for (int j = 0; j < 8; ++j) {
        u16 a = u0[j] > v0[j] ? u0[j] : v0[j]; m0[j] = m0[j] > a ? m0[j] : a;
        u16 b = u1[j] > v1[j] ? u1[j] : v1[j]; m1[j] = m1[j] > b ? m1[j] : b;
        u16 c = u2[j] > v2[j] ? u2[j] : v2[j]; m2[j] = m2[j] > c ? m2[j] : c;
      }
    } else {
#pragma unroll
      for (int j = 0; j < 8; ++j) {
        s0[j] += b2f((short)u0[j]) + b2f((short)v0[j]);
        s1[j] += b2f((short)u1[j]) + b2f((short)v1[j]);
        s2[j] += b2f((short)u2[j]) + b2f((short)v2[j]);
      }
    }
    i0 = n0; i1 = n1;
  }
  if (e < end) {
    size_t b0 = (size_t)i0 * 24 + cbase;
    u16x8 u0 = XH[b0], u1 = XH[b0 + 1], u2 = XH[b0 + 2];
    if (isMax) {
#pragma unroll
      for (int j = 0; j < 8; ++j) {
        m0[j] = m0[j] > u0[j] ? m0[j] : u0[j];
        m1[j] = m1[j] > u1[j] ? m1[j] : u1[j];
        m2[j] = m2[j] > u2[j] ? m2[j] : u2[j];
      }
    } else {
#pragma unroll
      for (int j = 0; j < 8; ++j) {
        s0[j] += b2f((short)u0[j]);
        s1[j] += b2f((short)u1[j]);
        s2[j] += b2f((short)u2[j]);
      }
    }
  }
  if (isMax) {
    // bf16 bit patterns pass through unchanged
    u16x8* dv = reinterpret_cast<u16x8*>(hxbf);
    size_t ob = (size_t)node * 12 + (slot - 4) * 3;
    dv[ob] = m0; dv[ob + 1] = m1; dv[ob + 2] = m2;
  } else {
    float scl = (end > beg) ? 1.0f / (float)(end - beg) : 0.0f;
    u16x8 w0, w1, w2;
#pragma unroll
    for (int j = 0; j < 8; ++j) {
      w0[j] = f2b(s0[j] * scl);
      w1[j] = f2b(s1[j] * scl);
      w2[j] = f2b(s2[j] * scl);
    }
    u16x8* dv = reinterpret_cast<u16x8*>(hmbf);
    size_t ob = (size_t)node * 12 + slot * 3;
    dv[ob] = w0; dv[ob + 1] = w1; dv[ob + 2] = w2;
  }
}

// ---------------- single-pass dual GEMM: stats + store o1/o2 bf16 in place ----------------
__global__ __launch_bounds__(1024) void dualgemm_kernel(const u16* __restrict__ xh,
                                                        u16* __restrict__ hmbf,
                                                        u16* __restrict__ hxbf,
                                                        const u16* __restrict__ wt,
                                                        float* __restrict__ stats) {
  __shared__ bf16x8 wl[4608];
  __shared__ float smst[384];
  int t = threadIdx.x;
  const bf16x8* wg = reinterpret_cast<const bf16x8*>(wt);
  for (int j = t; j < 4608; j += 1024) wl[j] = wg[j];
  for (int j = t; j < 384; j += 1024) smst[j] = 0.f;
  __syncthreads();
  int w = t >> 6, lane = t & 63;
  int i = lane & 15, g = lane >> 4;
  int row_base = blockIdx.x * 256 + w * 16;
  size_t arowx = (size_t)(row_base + i) * 24;
  size_t arowh = (size_t)(row_base + i) * 12;
  bf16x8 ax[3], am[3], ah[3];
#pragma unroll
  for (int kb = 0; kb < 3; ++kb) {
    ax[kb] = reinterpret_cast<const bf16x8*>(xh)[arowx + kb * 4 + g];
    am[kb] = reinterpret_cast<const bf16x8*>(hmbf)[arowh + kb * 4 + g];
    ah[kb] = reinterpret_cast<const bf16x8*>(hxbf)[arowh + kb * 4 + g];
  }
  __syncthreads();   // all reads of hm/hx done before in-place overwrite below
  for (int nt = 0; nt < 6; ++nt) {
    f32x4 a1 = {0.f, 0.f, 0.f, 0.f}, a2 = {0.f, 0.f, 0.f, 0.f};
    int bch = (nt * 16 + i) * 12;
#pragma unroll
    for (int kb = 0; kb < 3; ++kb) {
      int bc = bch + kb * 4 + g;
      a1 = MFMA16(ax[kb], wl[bc], a1, 0, 0, 0);
      a1 = MFMA16(am[kb], wl[1152 + bc], a1, 0, 0, 0);
      a2 = MFMA16(ax[kb], wl[2304 + bc], a2, 0, 0, 0);
      a2 = MFMA16(ah[kb], wl[3456 + bc], a2, 0, 0, 0);
    }
    int col = nt * 16 + i;
    float s1 = 0, q1 = 0, s2 = 0, q2 = 0;
#pragma unroll
    for (int r = 0; r < 4; ++r) {
      int grow = row_base + g * 4 + r;
      if (grow < NN) {
        float v = a1[r], u = a2[r];
        s1 += v; q1 += v * v; s2 += u; q2 += u * u;
        hmbf[(size_t)grow * 96 + col] = f2b(v);
        hxbf[(size_t)grow * 96 + col] = f2b(u);
      }
    }
    s1 += __shfl_xor(s1, 16); q1 += __shfl_xor(q1, 16);
    s2 += __shfl_xor(s2, 16); q2 += __shfl_xor(q2, 16);
    s1 += __shfl_xor(s1, 32); q1 += __shfl_xor(q1, 32);
    s2 += __shfl_xor(s2, 32); q2 += __shfl_xor(q2, 32);
    if (g == 0) {
      atomicAdd(&smst[col], s1);
      atomicAdd(&smst[96 + col], q1);
      atomicAdd(&smst[192 + col], s2);
      atomicAdd(&smst[288 + col], q2);
    }
  }
  __syncthreads();
  for (int j = t; j < 384; j += 1024) atomicAdd(&stats[j], smst[j]);
}

// ---------------- fold BN into per-column affine ----------------
__global__ void finalize_kernel(const float* __restrict__ stats,
                                const float* __restrict__ g1, const float* __restrict__ beta1,
                                const float* __restrict__ g2, const float* __restrict__ beta2,
                                float* __restrict__ params) {
  int c = threadIdx.x;
  if (c >= 96) return;
  const float inv_n = 1.0f / NN;
  float mu1 = stats[c] * inv_n;
  float var1 = fmaxf(stats[96 + c] * inv_n - mu1 * mu1, 0.0f);
  float is1 = rsqrtf(var1 + 1e-5f);
  float a1 = g1[c] * is1;
  params[c] = a1;
  params[96 + c] = beta1[c] - a1 * mu1;
  float mu2 = stats[192 + c] * inv_n;
  float var2 = fmaxf(stats[288 + c] * inv_n - mu2 * mu2, 0.0f);
  float is2 = rsqrtf(var2 + 1e-5f);
  float a2 = g2[c] * is2;
  params[192 + c] = a2;
  params[288 + c] = beta2[c] - a2 * mu2;
}

// ---------------- out = leaky(bn1(o1)+bn2(o2)), streaming ----------------
__global__ __launch_bounds__(256) void final_kernel(const u16* __restrict__ o1,
                                                    const u16* __restrict__ o2,
                                                    const float* __restrict__ params,
                                                    float* __restrict__ out) {
  int idx = blockIdx.x * 256 + threadIdx.x;   // one bf16x8 chunk
  if (idx >= NN * 12) return;
  int c8 = idx % 12;
  bf16x8 v1 = reinterpret_cast<const bf16x8*>(o1)[idx];
  bf16x8 v2 = reinterpret_cast<const bf16x8*>(o2)[idx];
  const float4* P = reinterpret_cast<const float4*>(params);
  float4 A1l = P[c8 * 2],      A1h = P[c8 * 2 + 1];
  float4 B1l = P[24 + c8 * 2], B1h = P[24 + c8 * 2 + 1];
  float4 A2l = P[48 + c8 * 2], A2h = P[48 + c8 * 2 + 1];
  float4 B2l = P[72 + c8 * 2], B2h = P[72 + c8 * 2 + 1];
  float A1[8] = {A1l.x, A1l.y, A1l.z, A1l.w, A1h.x, A1h.y, A1h.z, A1h.w};
  float B1[8] = {B1l.x, B1l.y, B1l.z, B1l.w, B1h.x, B1h.y, B1h.z, B1h.w};
  float A2[8] = {A2l.x, A2l.y, A2l.z, A2l.w, A2h.x, A2h.y, A2h.z, A2h.w};
  float B2[8] = {B2l.x, B2l.y, B2l.z, B2l.w, B2h.x, B2h.y, B2h.z, B2h.w};
  float o[8];
#pragma unroll
  for (int j = 0; j < 8; ++j) {
    float v = A1[j] * b2f(v1[j]) + B1[j] + A2[j] * b2f(v2[j]) + B2[j];
    o[j] = v > 0.f ? v : 0.01f * v;
  }
  float4* ov = reinterpret_cast<float4*>(out);
  float4 lo = {o[0], o[1], o[2], o[3]}, hi = {o[4], o[5], o[6], o[7]};
  ov[idx * 2] = lo;
  ov[idx * 2 + 1] = hi;
}

extern "C" void kernel_launch(void* const* d_in, const int* in_sizes, int n_in,
                              void* d_out, int out_size, void* d_ws, size_t ws_size,
                              hipStream_t stream) {
  const float* x       = (const float*)d_in[0];
  const int*   ei      = (const int*)d_in[1];
  const float* W_self1 = (const float*)d_in[2];
  const float* W_neigh1= (const float*)d_in[3];
  const float* W_pool  = (const float*)d_in[4];
  const float* b_pool  = (const float*)d_in[5];
  const float* W_self2 = (const float*)d_in[6];
  const float* W_neigh2= (const float*)d_in[7];
  const float* g1      = (const float*)d_in[8];
  const float* beta1   = (const float*)d_in[9];
  const float* g2      = (const float*)d_in[10];
  const float* beta2   = (const float*)d_in[11];
  float* out = (float*)d_out;

  float* ws = (float*)d_ws;
  int*   deg       = (int*)(ws + OFF_DEG);
  int*   row_start = (int*)(ws + OFF_ROWSTART);
  int*   cursor    = (int*)(ws + OFF_CURSOR);
  int*   bsum      = (int*)(ws + OFF_BSUM);
  float* stats     = ws + OFF_STATS;
  float* params    = ws + OFF_PARAMS;
  u16*   wt        = (u16*)(ws + OFF_WT);
  int*   csr       = (int*)(ws + OFF_CSR);
  u16*   xh        = (u16*)(ws + OFF_XH);
  u16*   hmbf      = (u16*)(ws + OFF_HMBF);
  u16*   hxbf      = (u16*)(ws + OFF_HXBF);

  const int* src = ei;
  const int* dst = ei + NE;

  hipMemsetAsync(deg, 0, NN * sizeof(int), stream);
  hipMemsetAsync(stats, 0, 384 * sizeof(float), stream);

  wprep_kernel<<<(5 * 9216 + 255) / 256, 256, 0, stream>>>(W_self1, W_neigh1, W_self2,
                                                           W_neigh2, W_pool, wt);

  deg_kernel<<<(NE + 255) / 256, 256, 0, stream>>>(dst, deg);
  scan_sum_kernel<<<SCAN_BLOCKS, 256, 0, stream>>>(deg, bsum);
  scan_bsum_kernel<<<1, 128, 0, stream>>>(bsum, row_start);
  scan_final_kernel<<<SCAN_BLOCKS, 256, 0, stream>>>(deg, bsum, row_start, cursor);
  fill_csr_kernel<<<(NE + 255) / 256, 256, 0, stream>>>(src, dst, cursor, csr);

  hp_gemm_kernel<<<GBLK, 512, 0, stream>>>(x, wt, b_pool, xh);

  gather_kernel<<<(NN + 31) / 32, 256, 0, stream>>>(xh, row_start, csr, hmbf, hxbf);

  dualgemm_kernel<<<DBLK, 1024, 0, stream>>>(xh, hmbf, hxbf, wt, stats);
  finalize_kernel<<<1, 128, 0, stream>>>(stats, g1, beta1, g2, beta2, params);
  final_kernel<<<(NN * 12 + 255) / 256, 256, 0, stream>>>(hmbf, hxbf, params, out);
}